// Round 8
// baseline (201.774 us; speedup 1.0000x reference)
//
#include <hip/hip_runtime.h>
#include <stdint.h>
#include <math.h>

typedef unsigned short u16;
typedef unsigned int u32;
typedef __attribute__((ext_vector_type(8))) short bf16x8;   // 8 bf16 (4 VGPRs) MFMA A/B frag
typedef __attribute__((ext_vector_type(4))) float f32x4;
typedef __attribute__((ext_vector_type(2))) float f32x2;
typedef __attribute__((ext_vector_type(2))) u16 u16x2;
typedef __attribute__((ext_vector_type(8))) u16 u16x8;
typedef __attribute__((ext_vector_type(2))) u32 u32x2;

#define B_ 8
#define T_ 1024
#define D_ 512
#define H_ 8
#define TP1 1025
// q scale: 1/sqrt(64) * log2(e)  (softmax runs in exp2 domain)
#define QSCALE 0.1803368801111204f

__device__ __forceinline__ u16 f2b(float f) {           // f32 -> bf16 RNE
  union { float f; u32 u; } v; v.f = f;
  return (u16)((v.u + 0x7fffu + ((v.u >> 16) & 1u)) >> 16);
}
__device__ __forceinline__ void gld16(const void* g, void* l) {
  // async global->LDS, 16B/lane; LDS dest = wave-uniform base + lane*16
  __builtin_amdgcn_global_load_lds((const __attribute__((address_space(1))) u32*)g,
                                   (__attribute__((address_space(3))) u32*)l, 16, 0, 0);
}
__device__ __forceinline__ f32x4 mfma16(bf16x8 a, bf16x8 b, f32x4 c) {
  return __builtin_amdgcn_mfma_f32_16x16x32_bf16(a, b, c, 0, 0, 0);
}
__device__ __forceinline__ u32 cvtpk(float lo, float hi) {   // 2xf32 -> packed bf16x2 (RNE)
  u32 r;
  asm("v_cvt_pk_bf16_f32 %0, %1, %2" : "=v"(r) : "v"(lo), "v"(hi));
  return r;
}
union U8 { u32 u[4]; bf16x8 v; };

// counted-vmcnt waits: wait for the OLDEST stage only, keep the rest in flight
#define WAITV(N) asm volatile("s_waitcnt vmcnt(" #N ")" ::: "memory")

// ---------------- fused prep: tiled (coalesced) weight transposes + rope tables ----------------
__global__ __launch_bounds__(256) void prep_kernel(const float* __restrict__ W_attn,
    const float* __restrict__ W1, const float* __restrict__ W2,
    const float* __restrict__ seq,
    u16* __restrict__ WtA, u16* __restrict__ W1i, u16* __restrict__ W2t,
    float* __restrict__ cq, float* __restrict__ sq_,
    float* __restrict__ ck, float* __restrict__ sk) {
  int bid = blockIdx.x, tid = threadIdx.x;
  if (bid >= 576) {                        // rope: B*T*16 elements
    int i = (bid - 576) * 256 + tid;
    int p = i & 15, bt = i >> 4, b = bt >> 10, t = bt & 1023;
    float inv = expf(-(float)p * 0.5756462732485115f);   // 10000^(-p/16)
    float aq = seq[b * TP1 + t] * inv;
    float ak = seq[b * TP1 + t + 1] * inv;
    cq[i] = cosf(aq); sq_[i] = sinf(aq);
    ck[i] = cosf(ak); sk[i] = sinf(ak);
    return;
  }
  __shared__ u16 lt[64][65];
  const float* src; u16* dst; int ld, Kd, k0, r0; bool ilv = false;
  if (bid < 192) {            // WtA: 8 k-tiles x 24 n-tiles
    src = W_attn; dst = WtA; ld = 1536; Kd = 512;
    k0 = (bid & 7) * 64; r0 = (bid >> 3) * 64;
  } else if (bid < 448) {     // W1i: 8 k-tiles x 32 r-tiles, interleaved
    int t = bid - 192;
    src = W1; dst = W1i; ld = 2048; Kd = 512; ilv = true;
    k0 = (t & 7) * 64; r0 = (t >> 3) * 64;
  } else {                    // W2t: 16 k-tiles x 8 n-tiles
    int t = bid - 448;
    src = W2; dst = W2t; ld = 512; Kd = 1024;
    k0 = (t & 15) * 64; r0 = (t >> 4) * 64;
  }
  int nl = tid & 63;
  int scol, rloc;
  if (ilv) {
    if (nl < 32) { scol = (r0 >> 1) + nl;          rloc = ((nl >> 4) << 5) + (nl & 15); }
    else         { scol = 1024 + (r0 >> 1) + (nl - 32); rloc = (((nl - 32) >> 4) << 5) + 16 + (nl & 15); }
  } else { scol = r0 + nl; rloc = nl; }
  #pragma unroll
  for (int it = 0; it < 16; it++) {
    int kl = (tid >> 6) * 16 + it;
    lt[rloc][kl] = f2b(src[(size_t)(k0 + kl) * ld + scol]);
  }
  __syncthreads();
  #pragma unroll
  for (int it = 0; it < 16; it++) {
    int rl = (tid >> 6) * 16 + it;
    dst[(size_t)(r0 + rl) * Kd + k0 + nl] = lt[rl][nl];
  }
}

// ---------------- LayerNorm: one WAVE per row, no LDS, no barriers ----------------
__global__ __launch_bounds__(256) void ln_kernel(const float* __restrict__ x,
    const float* __restrict__ g, const float* __restrict__ bta, u16* __restrict__ out) {
  int row = blockIdx.x * 4 + (threadIdx.x >> 6);    // 8192 rows, 4 rows/block
  int lane = threadIdx.x & 63;
  const float* xr = x + (size_t)row * D_ + lane * 8;
  f32x4 v0 = *(const f32x4*)xr;
  f32x4 v1 = *(const f32x4*)(xr + 4);
  float s = 0.f, sq = 0.f;
  #pragma unroll
  for (int j = 0; j < 4; j++) { s += v0[j] + v1[j]; sq += v0[j] * v0[j] + v1[j] * v1[j]; }
  #pragma unroll
  for (int m = 1; m < 64; m <<= 1) { s += __shfl_xor(s, m); sq += __shfl_xor(sq, m); }
  float mean = s * (1.f / D_);
  float var = sq * (1.f / D_) - mean * mean;
  float rstd = rsqrtf(var + 1e-5f);
  f32x4 g0 = *(const f32x4*)(g + lane * 8);
  f32x4 g1 = *(const f32x4*)(g + lane * 8 + 4);
  f32x4 b0 = *(const f32x4*)(bta + lane * 8);
  f32x4 b1 = *(const f32x4*)(bta + lane * 8 + 4);
  u16x8 o;
  #pragma unroll
  for (int j = 0; j < 4; j++) {
    o[j]     = f2b((v0[j] - mean) * rstd * g0[j] + b0[j]);
    o[4 + j] = f2b((v1[j] - mean) * rstd * g1[j] + b1[j]);
  }
  *(u16x8*)(out + (size_t)row * D_ + lane * 8) = o;
}

// ---------------- QKV GEMM with fused type-emb + RoPE + scale + head-layout epilogue ----------------
__global__ __launch_bounds__(256) void gemm_qkv(const u16* __restrict__ A,
    const u16* __restrict__ Bt,
    const int* __restrict__ x_type, const float* __restrict__ type_emb,
    const float* __restrict__ rqc, const float* __restrict__ rqs,
    const float* __restrict__ rkc, const float* __restrict__ rks,
    u16* __restrict__ qT, u16* __restrict__ kT, u16* __restrict__ vT) {
  __shared__ u16 lA[3][4096];
  __shared__ u16 lB[3][4096];
  const int K = 512, NK = 16;
  const int tid = threadIdx.x, lane = tid & 63, w = tid >> 6;
  const int wm = w >> 1, wn = w & 1;
  int swz = (blockIdx.x & 7) * 96 + (blockIdx.x >> 3);
  int byy = swz / 12, bxx = swz - byy * 12;
  const size_t bm = (size_t)byy * 128;
  const size_t bn = (size_t)bxx * 128;

  const int r0 = tid >> 2;
  const int cs = ((tid & 3) ^ ((r0 >> 1) & 3)) * 8;
  const u16* a0 = A + (bm + r0) * K + cs;
  const u16* a1 = A + (bm + 64 + r0) * K + cs;
  const u16* b0 = Bt + (bn + r0) * K + cs;
  const u16* b1p = Bt + (bn + 64 + r0) * K + cs;

  int aoff[4], boff[4];
  #pragma unroll
  for (int i = 0; i < 4; i++) {
    int ra = wm * 64 + i * 16 + (lane & 15);
    aoff[i] = ra * 64 + (((lane >> 4) ^ ((ra >> 1) & 3)) * 16);
    int rb = wn * 64 + i * 16 + (lane & 15);
    boff[i] = rb * 64 + (((lane >> 4) ^ ((rb >> 1) & 3)) * 16);
  }

  auto stage = [&](int j, int buf) {      // 4 loads
    char* ad = (char*)lA + buf * 8192 + w * 1024;
    char* bd = (char*)lB + buf * 8192 + w * 1024;
    gld16(a0 + j * 32, ad);
    gld16(a1 + j * 32, ad + 4096);
    gld16(b0 + j * 32, bd);
    gld16(b1p + j * 32, bd + 4096);
  };
  f32x4 acc[4][4] = {};
  auto compute = [&](int buf) {
    const char* lAc = (const char*)lA + buf * 8192;
    const char* lBc = (const char*)lB + buf * 8192;
    bf16x8 af[4], bf[4];
    #pragma unroll
    for (int i = 0; i < 4; i++) af[i] = *(const bf16x8*)(lAc + aoff[i]);
    #pragma unroll
    for (int n = 0; n < 4; n++) bf[n] = *(const bf16x8*)(lBc + boff[n]);
    __builtin_amdgcn_s_setprio(1);
    #pragma unroll
    for (int i = 0; i < 4; i++)
      #pragma unroll
      for (int n = 0; n < 4; n++)
        acc[i][n] = mfma16(af[i], bf[n], acc[i][n]);
    __builtin_amdgcn_s_setprio(0);
  };

  stage(0, 0);
  stage(1, 1);
  int cur = 0;
  for (int j = 0; j < NK - 1; j++) {
    WAITV(4);
    __builtin_amdgcn_s_barrier();
    if (j + 2 < NK) { int nb = cur + 2; if (nb >= 3) nb -= 3; stage(j + 2, nb); }
    compute(cur);
    cur = (cur + 1 == 3) ? 0 : cur + 1;
  }
  WAITV(0);
  __builtin_amdgcn_s_barrier();
  compute(cur);

  // fused epilogue. block-uniform region: 0=q (cols 0..511), 1=k, 2=v
  const int region = (int)(bn >> 9);
  #pragma unroll
  for (int i = 0; i < 4; i++) {
    #pragma unroll
    for (int jj = 0; jj < 4; jj++) {
      int row = (int)bm + wm * 64 + i * 16 + (lane >> 4) * 4 + jj;   // bt index
      int b = row >> 10, t = row & 1023;
      if (region == 0) {
        int ty = x_type[b * TP1 + t];
        #pragma unroll
        for (int n = 0; n < 4; n++) {
          int cloc = (int)bn + wn * 64 + n * 16 + (lane & 15);       // 0..511
          int h = cloc >> 6, hd = cloc & 63;
          float v = acc[i][n][jj] + type_emb[(size_t)ty * 1024 + cloc];
          float vp = __shfl_xor(v, 1);
          if (hd < 32) {
            int p = hd >> 1;
            float c = rqc[row * 16 + p], s = rqs[row * 16 + p];
            v = (hd & 1) ? (v * c + vp * s) : (v * c - vp * s);
          }
          qT[((size_t)(b * 8 + h) * T_ + t) * 64 + hd] = f2b(v * QSCALE);
        }
      } else if (region == 1) {
        int ty = x_type[b * TP1 + t + 1];
        #pragma unroll
        for (int n = 0; n < 4; n++) {
          int cloc = (int)bn - 512 + wn * 64 + n * 16 + (lane & 15); // 0..511
          int h = cloc >> 6, hd = cloc & 63;
          float v = acc[i][n][jj] + type_emb[(size_t)ty * 1024 + 512 + cloc];
          float vp = __shfl_xor(v, 1);
          if (hd < 32) {
            int p = hd >> 1;
            float c = rkc[row * 16 + p], s = rks[row * 16 + p];
            v = (hd & 1) ? (v * c + vp * s) : (v * c - vp * s);
          }
          kT[((size_t)(b * 8 + h) * T_ + t) * 64 + hd] = f2b(v);
        }
      } else {
        #pragma unroll
        for (int n = 0; n < 4; n++) {
          int cloc = (int)bn - 1024 + wn * 64 + n * 16 + (lane & 15);
          int h = cloc >> 6, hd = cloc & 63;
          vT[((size_t)(b * 8 + h) * 64 + hd) * T_ + t] = f2b(acc[i][n][jj]);
        }
      }
    }
  }
}

// ---------------- FF1 GEMM: 256x256 tile, 8 waves, 2-phase, in-lane SwiGLU ----------------
// wave (wm,wn) of 2x4 owns a 128x64 output sub-tile; 32 MFMA per K-step.
__global__ __launch_bounds__(512) void gemm_ff1(const u16* __restrict__ A,
    const u16* __restrict__ Bt, const float* __restrict__ b1,
    u16* __restrict__ outp) {
  __shared__ u16 lA[2][8192];
  __shared__ u16 lB[2][8192];
  const int K = 512;
  const int tid = threadIdx.x, lane = tid & 63, w = tid >> 6;   // 0..7
  const int wm = w >> 2, wn = w & 3;
  int swz = (blockIdx.x & 7) * 32 + (blockIdx.x >> 3);          // 256 blocks
  int byy = swz >> 3, bxx = swz & 7;                            // 32 x 8
  const size_t bm = (size_t)byy * 256;
  const size_t bn = (size_t)bxx * 256;

  const int r0 = tid >> 2;                                      // 0..127
  const int cs = ((tid & 3) ^ ((r0 >> 1) & 3)) * 8;
  const u16* a0 = A + (bm + r0) * K + cs;
  const u16* a1 = A + (bm + 128 + r0) * K + cs;
  const u16* b0 = Bt + (bn + r0) * K + cs;
  const u16* b1p = Bt + (bn + 128 + r0) * K + cs;

  int aoff[8], boff[4];
  #pragma unroll
  for (int i = 0; i < 8; i++) {
    int ra = wm * 128 + i * 16 + (lane & 15);
    aoff[i] = ra * 64 + (((lane >> 4) ^ ((ra >> 1) & 3)) * 16);
  }
  #pragma unroll
  for (int n = 0; n < 4; n++) {
    int rb = wn * 64 + n * 16 + (lane & 15);
    boff[n] = rb * 64 + (((lane >> 4) ^ ((rb >> 1) & 3)) * 16);
  }

  auto stage = [&](int k0, int buf) {
    char* ad = (char*)lA + buf * 16384 + w * 1024;
    char* bd = (char*)lB + buf * 16384 + w * 1024;
    gld16(a0 + k0, ad);
    gld16(a1 + k0, ad + 8192);
    gld16(b0 + k0, bd);
    gld16(b1p + k0, bd + 8192);
  };

  f32x4 acc[8][4] = {};
  stage(0, 0);
  __syncthreads();
  int cur = 0;
  for (int k0 = 0; k0 < K; k0 += 32) {
    if (k0 + 32 < K) stage(k0 + 32, cur ^ 1);
    const char* lAc = (const char*)lA + cur * 16384;
    const char* lBc = (const char*)lB + cur * 16384;
    bf16x8 bf[4];
    #pragma unroll
    for (int n = 0; n < 4; n++) bf[n] = *(const bf16x8*)(lBc + boff[n]);
    __builtin_amdgcn_s_setprio(1);
    #pragma unroll
    for (int i = 0; i < 8; i++) {
      bf16x8 af = *(const bf16x8*)(lAc + aoff[i]);
      #pragma unroll
      for (int n = 0; n < 4; n++)
        acc[i][n] = mfma16(af, bf[n], acc[i][n]);
    }
    __builtin_amdgcn_s_setprio(0);
    __syncthreads();
    cur ^= 1;
  }
  // epilogue: real col c = bn/2 + wn*32 + np*16 + q; a = acc[i][2np], g = acc[i][2np+1]
  #pragma unroll
  for (int np = 0; np < 2; np++) {
    int c = ((int)bn >> 1) + wn * 32 + np * 16 + (lane & 15);
    float bav = b1[c], bgv = b1[1024 + c];
    #pragma unroll
    for (int i = 0; i < 8; i++) {
      #pragma unroll
      for (int jj = 0; jj < 4; jj++) {
        int row = (int)bm + wm * 128 + i * 16 + (lane >> 4) * 4 + jj;
        float av = acc[i][2 * np][jj] + bav;
        float gv = acc[i][2 * np + 1][jj] + bgv;
        float sg = gv / (1.f + expf(-gv));
        outp[(size_t)row * 1024 + c] = f2b(sg * av);
      }
    }
  }
}

// ---------------- FF2 GEMM, 512 thr / 8 waves, 3-deep counted pipeline ----------------
__global__ __launch_bounds__(512) void gemm_ff2(const u16* __restrict__ A,
    const u16* __restrict__ Bt, const float* __restrict__ bias,
    float* __restrict__ C) {
  __shared__ u16 lA[3][4096];
  __shared__ u16 lB[3][4096];
  const int K = 1024, N = 512, NK = 32;
  const int tid = threadIdx.x, lane = tid & 63, w = tid >> 6;   // w 0..7
  const int wm = w >> 2, wn = w & 3;                            // 2x4 waves: 64x32 each
  int swz = (blockIdx.x & 7) * 32 + (blockIdx.x >> 3);          // 256 blocks
  int byy = swz >> 2, bxx = swz & 3;
  const size_t bm = (size_t)byy * 128;
  const size_t bn = (size_t)bxx * 128;

  const int r0 = tid >> 2;                                      // 0..127
  const int cs = ((tid & 3) ^ ((r0 >> 1) & 3)) * 8;
  const u16* a0 = A + (bm + r0) * K + cs;
  const u16* b0 = Bt + (bn + r0) * K + cs;

  int aoff[4], boff[2];
  #pragma unroll
  for (int i = 0; i < 4; i++) {
    int ra = wm * 64 + i * 16 + (lane & 15);
    aoff[i] = ra * 64 + (((lane >> 4) ^ ((ra >> 1) & 3)) * 16);
  }
  #pragma unroll
  for (int n = 0; n < 2; n++) {
    int rb = wn * 32 + n * 16 + (lane & 15);
    boff[n] = rb * 64 + (((lane >> 4) ^ ((rb >> 1) & 3)) * 16);
  }

  auto stage = [&](int j, int buf) {      // 2 loads
    gld16(a0 + j * 32, (char*)lA + buf * 8192 + w * 1024);
    gld16(b0 + j * 32, (char*)lB + buf * 8192 + w * 1024);
  };
  f32x4 acc[4][2] = {};
  auto compute = [&](int buf) {
    const char* lAc = (const char*)lA + buf * 8192;
    const char* lBc = (const char*)lB + buf * 8192;
    bf16x8 af[4], bf[2];
    #pragma unroll
    for (int i = 0; i < 4; i++) af[i] = *(const bf16x8*)(lAc + aoff[i]);
    #pragma unroll
    for (int n = 0; n < 2; n++) bf[n] = *(const bf16x8*)(lBc + boff[n]);
    __builtin_amdgcn_s_setprio(1);
    #pragma unroll
    for (int i = 0; i < 4; i++)
      #pragma unroll
      for (int n = 0; n < 2; n++)
        acc[i][n] = mfma16(af[i], bf[n], acc[i][n]);
    __builtin_amdgcn_s_setprio(0);
  };

  stage(0, 0);
  stage(1, 1);
  int cur = 0;
  for (int j = 0; j < NK - 1; j++) {
    WAITV(2);
    __builtin_amdgcn_s_barrier();
    if (j + 2 < NK) { int nb = cur + 2; if (nb >= 3) nb -= 3; stage(j + 2, nb); }
    compute(cur);
    cur = (cur + 1 == 3) ? 0 : cur + 1;
  }
  WAITV(0);
  __builtin_amdgcn_s_barrier();
  compute(cur);

  #pragma unroll
  for (int i = 0; i < 4; i++) {
    size_t mrow = bm + wm * 64 + i * 16 + (lane >> 4) * 4;
    #pragma unroll
    for (int n = 0; n < 2; n++) {
      size_t col = bn + wn * 32 + n * 16 + (lane & 15);
      float bv = bias[col];
      #pragma unroll
      for (int jj = 0; jj < 4; jj++) {
        size_t idx = (mrow + jj) * (size_t)N + col;
        C[idx] = acc[i][n][jj] + bv + C[idx];   // in-place residual
      }
    }
  }
}

// ---------------- causal flash attention + residual: barrier-free, LDS-free ----------------
// One WAVE per (bh, 16-row q-strip). K/V read directly from L2 (per-XCD KV = 2MB,
// L2-resident; guide CM#7: don't LDS-stage L2-fitting data). Next-tile K prefetch
// via WAR ordering; V loads issued before QK so latency hides under QK+softmax.
// No __syncthreads anywhere: waves free-run, SIMD overlaps softmax with MFMA.
__global__ __launch_bounds__(256) void attn_kernel(const u16* __restrict__ qT,
    const u16* __restrict__ kT, const u16* __restrict__ vT,
    const float* __restrict__ xv, float* __restrict__ X) {
  const int w = threadIdx.x >> 6, lane = threadIdx.x & 63;
  const int f = ((int)blockIdx.x >> 3) * 4 + w;           // 0..511 within XCD
  const int xcd = blockIdx.x & 7;
  const int bh = xcd * 8 + (f & 7);                       // 8 bh per XCD (KV L2 locality)
  const int sp = 63 - (f >> 3);                           // LPT: long strips first
  const int b = bh >> 3, h = bh & 7;
  const int q = lane & 15, g = lane >> 4;
  const int qrow0 = sp * 16;
  const int jmax = (sp >> 2) + 1;

  bf16x8 qf[2];
  {
    const u16* qp_ = qT + ((size_t)bh * T_ + qrow0 + q) * 64 + g * 8;
    qf[0] = *(const bf16x8*)qp_;
    qf[1] = *(const bf16x8*)(qp_ + 32);
  }
  // per-lane base pointers (k/v tile offsets become immediates)
  const u16* kl = kT + (size_t)bh * 65536 + q * 64 + g * 8;          // row q, col g*8
  const u16* vl = vT + (size_t)bh * 65536 + (size_t)q * 1024 + g * 4; // d-row q, col g*4

  f32x4 acc[4] = {};
  float mr = -1e30f, lr = 0.f;

  // prologue: K frags for tile 0
  bf16x8 kc[8];
  #pragma unroll
  for (int n = 0; n < 4; n++)
    #pragma unroll
    for (int ka = 0; ka < 2; ka++)
      kc[n * 2 + ka] = *(const bf16x8*)(kl + n * 1024 + ka * 32);

  for (int j = 0; j < jmax; j++) {
    // V loads for tile j (latency hides under QK + softmax)
    u32x2 vlo[8], vhi[8];
    #pragma unroll
    for (int t = 0; t < 4; t++) {
      const u16* vp = vl + (size_t)t * 16384 + j * 64;
      #pragma unroll
      for (int kt = 0; kt < 2; kt++) {
        vlo[t * 2 + kt] = *(const u32x2*)(vp + kt * 32);
        vhi[t * 2 + kt] = *(const u32x2*)(vp + kt * 32 + 16);
      }
    }
    // QK^T swapped: s[n][i] = S[k = j*64 + n*16+g*4+i][qrow0+q]
    f32x4 s[4] = {};
    __builtin_amdgcn_s_setprio(1);
    #pragma unroll
    for (int ka = 0; ka < 2; ka++)
      #pragma unroll
      for (int n = 0; n < 4; n++)
        s[n] = mfma16(kc[n * 2 + ka], qf[ka], s[n]);
    __builtin_amdgcn_s_setprio(0);
    // prefetch next tile's K frags (WAR on kc orders these after the MFMAs;
    // loads land during softmax+PV of this tile)
    if (j + 1 < jmax) {
      const u16* kn = kl + (size_t)(j + 1) * 4096;
      #pragma unroll
      for (int n = 0; n < 4; n++)
        #pragma unroll
        for (int ka = 0; ka < 2; ka++)
          kc[n * 2 + ka] = *(const bf16x8*)(kn + n * 1024 + ka * 32);
    }
    if (j == jmax - 1) {                   // diagonal tile mask
      int qrow = qrow0 + q;
      #pragma unroll
      for (int n = 0; n < 4; n++)
        #pragma unroll
        for (int i = 0; i < 4; i++)
          if (j * 64 + n * 16 + g * 4 + i > qrow) s[n][i] = -1e30f;
    }
    // in-register softmax: one q-row per lane (+2 shfl across g-groups)
    float mt = fmaxf(fmaxf(fmaxf(s[0][0], s[0][1]), fmaxf(s[0][2], s[0][3])),
                     fmaxf(fmaxf(s[1][0], s[1][1]), fmaxf(s[1][2], s[1][3])));
    mt = fmaxf(mt, fmaxf(fmaxf(fmaxf(s[2][0], s[2][1]), fmaxf(s[2][2], s[2][3])),
                         fmaxf(fmaxf(s[3][0], s[3][1]), fmaxf(s[3][2], s[3][3]))));
    mt = fmaxf(mt, __shfl_xor(mt, 16));
    mt = fmaxf(mt, __shfl_xor(mt, 32));
    if (__any(mt > mr + 8.f)) {            // defer-max: skip rescale when growth < 2^8
      float mnew = fmaxf(mr, mt);
      float sc = exp2f(mr - mnew);
      mr = mnew;
      lr *= sc;
      #pragma unroll
      for (int t = 0; t < 4; t++) acc[t] *= sc;
    }
    float p[4][4];
    float ps = 0.f;
    #pragma unroll
    for (int n = 0; n < 4; n++)
      #pragma unroll
      for (int i = 0; i < 4; i++) { p[n][i] = exp2f(s[n][i] - mr); ps += p[n][i]; }
    ps += __shfl_xor(ps, 16);
    ps += __shfl_xor(ps, 32);
    lr += ps;
    // pack P into PV B-frags (lane-local, no shuffles)
    U8 pa[2];
    #pragma unroll
    for (int kt = 0; kt < 2; kt++) {
      pa[kt].u[0] = cvtpk(p[2 * kt][0], p[2 * kt][1]);
      pa[kt].u[1] = cvtpk(p[2 * kt][2], p[2 * kt][3]);
      pa[kt].u[2] = cvtpk(p[2 * kt + 1][0], p[2 * kt + 1][1]);
      pa[kt].u[3] = cvtpk(p[2 * kt + 1][2], p[2 * kt + 1][3]);
    }
    // PV: O^T[d][q] += V^T[d][k'] * P^T[k'][q], k'(g,e) = kt*32+(e>>2)*16+g*4+(e&3)
    __builtin_amdgcn_s_setprio(1);
    #pragma unroll
    for (int t = 0; t < 4; t++) {
      #pragma unroll
      for (int kt = 0; kt < 2; kt++) {
        U8 af;
        af.u[0] = vlo[t * 2 + kt][0]; af.u[1] = vlo[t * 2 + kt][1];
        af.u[2] = vhi[t * 2 + kt][0]; af.u[3] = vhi[t * 2 + kt][1];
        acc[t] = mfma16(af.v, pa[kt].v, acc[t]);
      }
    }
    __builtin_amdgcn_s_setprio(0);
  }
  // epilogue: lane owns q-row (qrow0+q), cols d = t*16+g*4+{0..3} -> f32x4
  {
    float inv = 1.f / lr;
    size_t base = ((size_t)b * T_ + qrow0 + q) * D_ + h * 64 + g * 4;
    #pragma unroll
    for (int t = 0; t < 4; t++) {
      f32x4 r = *(const f32x4*)(xv + base + t * 16);
      f32x4 o;
      #pragma unroll
      for (int i = 0; i < 4; i++) o[i] = r[i] + acc[t][i] * inv;
      *(f32x4*)(X + base + t * 16) = o;
    }
  }
}

// ------------------------------- launch -------------------------------
extern "C" void kernel_launch(void* const* d_in, const int* in_sizes, int n_in,
                              void* d_out, int out_size, void* d_ws, size_t ws_size,
                              hipStream_t stream) {
  const int*   x_type   = (const int*)d_in[0];
  const float* x_value  = (const float*)d_in[1];
  const float* seq      = (const float*)d_in[2];
  const float* W_attn   = (const float*)d_in[3];
  const float* type_emb = (const float*)d_in[4];
  const float* ln1_g    = (const float*)d_in[5];
  const float* ln1_b    = (const float*)d_in[6];
  const float* ln2_g    = (const float*)d_in[7];
  const float* ln2_b    = (const float*)d_in[8];
  const float* W1       = (const float*)d_in[9];
  const float* b1       = (const float*)d_in[10];
  const float* W2       = (const float*)d_in[11];
  const float* b2       = (const float*)d_in[12];
  float* out = (float*)d_out;
  char* ws = (char*)d_ws;

  // workspace layout — total ~38.5 MiB
  u16*   WtA  = (u16*)(ws + 0);             // 1536x512 bf16  1.5 MiB
  u16*   W1i  = (u16*)(ws + 1572864);       // 2048x512 bf16 interleaved a/gate  2 MiB
  u16*   W2t  = (u16*)(ws + 3670016);       // 512x1024 bf16  1 MiB
  float* rqc  = (float*)(ws + 4718592);     // 4 rope tables, 512 KiB each
  float* rqs  = (float*)(ws + 5242880);
  float* rkc  = (float*)(ws + 5767168);
  float* rks  = (float*)(ws + 6291456);
  u16*   hbuf = (u16*)(ws + 6815744);       // 8192x512 bf16 (h, then h2)  8 MiB
  u16*   qTb  = (u16*)(ws + 15204352);      // (B,H,T,64) bf16  8 MiB
  u16*   kTb  = (u16*)(ws + 23592960);      // 8 MiB
  u16*   vTb  = (u16*)(ws + 31981568);      // (B,H,64,T) bf16  8 MiB
  u16*   ff1a = (u16*)(ws + 15204352);      // 8192x1024 bf16 16 MiB, aliases qT+kT (dead post-attn)

  prep_kernel<<<1088, 256, 0, stream>>>(W_attn, W1, W2, seq, WtA, W1i, W2t,
                                        rqc, rqs, rkc, rks);
  ln_kernel<<<B_ * T_ / 4, 256, 0, stream>>>(x_value, ln1_g, ln1_b, hbuf);
  gemm_qkv<<<768, 256, 0, stream>>>(hbuf, WtA, x_type, type_emb,
                                    rqc, rqs, rkc, rks, qTb, kTb, vTb);
  attn_kernel<<<1024, 256, 0, stream>>>(qTb, kTb, vTb, x_value, out);
  ln_kernel<<<B_ * T_ / 4, 256, 0, stream>>>(out, ln2_g, ln2_b, hbuf);
  gemm_ff1<<<256, 512, 0, stream>>>(hbuf, W1i, b1, ff1a);
  gemm_ff2<<<256, 512, 0, stream>>>(ff1a, W2t, b2, out);
}

// Round 9
// 151.542 us; speedup vs baseline: 1.3315x; 1.3315x over previous
//
#include <hip/hip_runtime.h>
#include <stdint.h>
#include <math.h>

typedef unsigned short u16;
typedef unsigned int u32;
typedef __attribute__((ext_vector_type(8))) short bf16x8;   // 8 bf16 (4 VGPRs) MFMA A/B frag
typedef __attribute__((ext_vector_type(4))) float f32x4;
typedef __attribute__((ext_vector_type(2))) float f32x2;
typedef __attribute__((ext_vector_type(2))) u16 u16x2;
typedef __attribute__((ext_vector_type(8))) u16 u16x8;
typedef __attribute__((ext_vector_type(2))) u32 u32x2;

#define B_ 8
#define T_ 1024
#define D_ 512
#define H_ 8
#define TP1 1025
// q scale: 1/sqrt(64) * log2(e)  (softmax runs in exp2 domain)
#define QSCALE 0.1803368801111204f

__device__ __forceinline__ u16 f2b(float f) {           // f32 -> bf16 RNE
  union { float f; u32 u; } v; v.f = f;
  return (u16)((v.u + 0x7fffu + ((v.u >> 16) & 1u)) >> 16);
}
__device__ __forceinline__ void gld16(const void* g, void* l) {
  // async global->LDS, 16B/lane; LDS dest = wave-uniform base + lane*16
  __builtin_amdgcn_global_load_lds((const __attribute__((address_space(1))) u32*)g,
                                   (__attribute__((address_space(3))) u32*)l, 16, 0, 0);
}
__device__ __forceinline__ f32x4 mfma16(bf16x8 a, bf16x8 b, f32x4 c) {
  return __builtin_amdgcn_mfma_f32_16x16x32_bf16(a, b, c, 0, 0, 0);
}
__device__ __forceinline__ u32 cvtpk(float lo, float hi) {   // 2xf32 -> packed bf16x2 (RNE)
  u32 r;
  asm("v_cvt_pk_bf16_f32 %0, %1, %2" : "=v"(r) : "v"(lo), "v"(hi));
  return r;
}
union U8 { u32 u[4]; bf16x8 v; };

// counted-vmcnt waits: wait for the OLDEST stage only, keep the rest in flight
#define WAITV(N) asm volatile("s_waitcnt vmcnt(" #N ")" ::: "memory")

// ---------------- fused prep: tiled (coalesced) weight transposes + rope tables ----------------
__global__ __launch_bounds__(256) void prep_kernel(const float* __restrict__ W_attn,
    const float* __restrict__ W1, const float* __restrict__ W2,
    const float* __restrict__ seq,
    u16* __restrict__ WtA, u16* __restrict__ W1i, u16* __restrict__ W2t,
    float* __restrict__ cq, float* __restrict__ sq_,
    float* __restrict__ ck, float* __restrict__ sk) {
  int bid = blockIdx.x, tid = threadIdx.x;
  if (bid >= 576) {                        // rope: B*T*16 elements
    int i = (bid - 576) * 256 + tid;
    int p = i & 15, bt = i >> 4, b = bt >> 10, t = bt & 1023;
    float inv = expf(-(float)p * 0.5756462732485115f);   // 10000^(-p/16)
    float aq = seq[b * TP1 + t] * inv;
    float ak = seq[b * TP1 + t + 1] * inv;
    cq[i] = cosf(aq); sq_[i] = sinf(aq);
    ck[i] = cosf(ak); sk[i] = sinf(ak);
    return;
  }
  __shared__ u16 lt[64][65];
  const float* src; u16* dst; int ld, Kd, k0, r0; bool ilv = false;
  if (bid < 192) {            // WtA: 8 k-tiles x 24 n-tiles
    src = W_attn; dst = WtA; ld = 1536; Kd = 512;
    k0 = (bid & 7) * 64; r0 = (bid >> 3) * 64;
  } else if (bid < 448) {     // W1i: 8 k-tiles x 32 r-tiles, interleaved
    int t = bid - 192;
    src = W1; dst = W1i; ld = 2048; Kd = 512; ilv = true;
    k0 = (t & 7) * 64; r0 = (t >> 3) * 64;
  } else {                    // W2t: 16 k-tiles x 8 n-tiles
    int t = bid - 448;
    src = W2; dst = W2t; ld = 512; Kd = 1024;
    k0 = (t & 15) * 64; r0 = (t >> 4) * 64;
  }
  int nl = tid & 63;
  int scol, rloc;
  if (ilv) {
    if (nl < 32) { scol = (r0 >> 1) + nl;          rloc = ((nl >> 4) << 5) + (nl & 15); }
    else         { scol = 1024 + (r0 >> 1) + (nl - 32); rloc = (((nl - 32) >> 4) << 5) + 16 + (nl & 15); }
  } else { scol = r0 + nl; rloc = nl; }
  #pragma unroll
  for (int it = 0; it < 16; it++) {
    int kl = (tid >> 6) * 16 + it;
    lt[rloc][kl] = f2b(src[(size_t)(k0 + kl) * ld + scol]);
  }
  __syncthreads();
  #pragma unroll
  for (int it = 0; it < 16; it++) {
    int rl = (tid >> 6) * 16 + it;
    dst[(size_t)(r0 + rl) * Kd + k0 + nl] = lt[rl][nl];
  }
}

// ---------------- LayerNorm: one WAVE per row, no LDS, no barriers ----------------
__global__ __launch_bounds__(256) void ln_kernel(const float* __restrict__ x,
    const float* __restrict__ g, const float* __restrict__ bta, u16* __restrict__ out) {
  int row = blockIdx.x * 4 + (threadIdx.x >> 6);    // 8192 rows, 4 rows/block
  int lane = threadIdx.x & 63;
  const float* xr = x + (size_t)row * D_ + lane * 8;
  f32x4 v0 = *(const f32x4*)xr;
  f32x4 v1 = *(const f32x4*)(xr + 4);
  float s = 0.f, sq = 0.f;
  #pragma unroll
  for (int j = 0; j < 4; j++) { s += v0[j] + v1[j]; sq += v0[j] * v0[j] + v1[j] * v1[j]; }
  #pragma unroll
  for (int m = 1; m < 64; m <<= 1) { s += __shfl_xor(s, m); sq += __shfl_xor(sq, m); }
  float mean = s * (1.f / D_);
  float var = sq * (1.f / D_) - mean * mean;
  float rstd = rsqrtf(var + 1e-5f);
  f32x4 g0 = *(const f32x4*)(g + lane * 8);
  f32x4 g1 = *(const f32x4*)(g + lane * 8 + 4);
  f32x4 b0 = *(const f32x4*)(bta + lane * 8);
  f32x4 b1 = *(const f32x4*)(bta + lane * 8 + 4);
  u16x8 o;
  #pragma unroll
  for (int j = 0; j < 4; j++) {
    o[j]     = f2b((v0[j] - mean) * rstd * g0[j] + b0[j]);
    o[4 + j] = f2b((v1[j] - mean) * rstd * g1[j] + b1[j]);
  }
  *(u16x8*)(out + (size_t)row * D_ + lane * 8) = o;
}

// ---------------- QKV GEMM with fused type-emb + RoPE + scale + head-layout epilogue ----------------
__global__ __launch_bounds__(256) void gemm_qkv(const u16* __restrict__ A,
    const u16* __restrict__ Bt,
    const int* __restrict__ x_type, const float* __restrict__ type_emb,
    const float* __restrict__ rqc, const float* __restrict__ rqs,
    const float* __restrict__ rkc, const float* __restrict__ rks,
    u16* __restrict__ qT, u16* __restrict__ kT, u16* __restrict__ vT) {
  __shared__ u16 lA[3][4096];
  __shared__ u16 lB[3][4096];
  const int K = 512, NK = 16;
  const int tid = threadIdx.x, lane = tid & 63, w = tid >> 6;
  const int wm = w >> 1, wn = w & 1;
  int swz = (blockIdx.x & 7) * 96 + (blockIdx.x >> 3);
  int byy = swz / 12, bxx = swz - byy * 12;
  const size_t bm = (size_t)byy * 128;
  const size_t bn = (size_t)bxx * 128;

  const int r0 = tid >> 2;
  const int cs = ((tid & 3) ^ ((r0 >> 1) & 3)) * 8;
  const u16* a0 = A + (bm + r0) * K + cs;
  const u16* a1 = A + (bm + 64 + r0) * K + cs;
  const u16* b0 = Bt + (bn + r0) * K + cs;
  const u16* b1p = Bt + (bn + 64 + r0) * K + cs;

  int aoff[4], boff[4];
  #pragma unroll
  for (int i = 0; i < 4; i++) {
    int ra = wm * 64 + i * 16 + (lane & 15);
    aoff[i] = ra * 64 + (((lane >> 4) ^ ((ra >> 1) & 3)) * 16);
    int rb = wn * 64 + i * 16 + (lane & 15);
    boff[i] = rb * 64 + (((lane >> 4) ^ ((rb >> 1) & 3)) * 16);
  }

  auto stage = [&](int j, int buf) {      // 4 loads
    char* ad = (char*)lA + buf * 8192 + w * 1024;
    char* bd = (char*)lB + buf * 8192 + w * 1024;
    gld16(a0 + j * 32, ad);
    gld16(a1 + j * 32, ad + 4096);
    gld16(b0 + j * 32, bd);
    gld16(b1p + j * 32, bd + 4096);
  };
  f32x4 acc[4][4] = {};
  auto compute = [&](int buf) {
    const char* lAc = (const char*)lA + buf * 8192;
    const char* lBc = (const char*)lB + buf * 8192;
    bf16x8 af[4], bf[4];
    #pragma unroll
    for (int i = 0; i < 4; i++) af[i] = *(const bf16x8*)(lAc + aoff[i]);
    #pragma unroll
    for (int n = 0; n < 4; n++) bf[n] = *(const bf16x8*)(lBc + boff[n]);
    __builtin_amdgcn_s_setprio(1);
    #pragma unroll
    for (int i = 0; i < 4; i++)
      #pragma unroll
      for (int n = 0; n < 4; n++)
        acc[i][n] = mfma16(af[i], bf[n], acc[i][n]);
    __builtin_amdgcn_s_setprio(0);
  };

  stage(0, 0);
  stage(1, 1);
  int cur = 0;
  for (int j = 0; j < NK - 1; j++) {
    WAITV(4);
    __builtin_amdgcn_s_barrier();
    if (j + 2 < NK) { int nb = cur + 2; if (nb >= 3) nb -= 3; stage(j + 2, nb); }
    compute(cur);
    cur = (cur + 1 == 3) ? 0 : cur + 1;
  }
  WAITV(0);
  __builtin_amdgcn_s_barrier();
  compute(cur);

  // fused epilogue. block-uniform region: 0=q (cols 0..511), 1=k, 2=v
  const int region = (int)(bn >> 9);
  #pragma unroll
  for (int i = 0; i < 4; i++) {
    #pragma unroll
    for (int jj = 0; jj < 4; jj++) {
      int row = (int)bm + wm * 64 + i * 16 + (lane >> 4) * 4 + jj;   // bt index
      int b = row >> 10, t = row & 1023;
      if (region == 0) {
        int ty = x_type[b * TP1 + t];
        #pragma unroll
        for (int n = 0; n < 4; n++) {
          int cloc = (int)bn + wn * 64 + n * 16 + (lane & 15);       // 0..511
          int h = cloc >> 6, hd = cloc & 63;
          float v = acc[i][n][jj] + type_emb[(size_t)ty * 1024 + cloc];
          float vp = __shfl_xor(v, 1);
          if (hd < 32) {
            int p = hd >> 1;
            float c = rqc[row * 16 + p], s = rqs[row * 16 + p];
            v = (hd & 1) ? (v * c + vp * s) : (v * c - vp * s);
          }
          qT[((size_t)(b * 8 + h) * T_ + t) * 64 + hd] = f2b(v * QSCALE);
        }
      } else if (region == 1) {
        int ty = x_type[b * TP1 + t + 1];
        #pragma unroll
        for (int n = 0; n < 4; n++) {
          int cloc = (int)bn - 512 + wn * 64 + n * 16 + (lane & 15); // 0..511
          int h = cloc >> 6, hd = cloc & 63;
          float v = acc[i][n][jj] + type_emb[(size_t)ty * 1024 + 512 + cloc];
          float vp = __shfl_xor(v, 1);
          if (hd < 32) {
            int p = hd >> 1;
            float c = rkc[row * 16 + p], s = rks[row * 16 + p];
            v = (hd & 1) ? (v * c + vp * s) : (v * c - vp * s);
          }
          kT[((size_t)(b * 8 + h) * T_ + t) * 64 + hd] = f2b(v);
        }
      } else {
        #pragma unroll
        for (int n = 0; n < 4; n++) {
          int cloc = (int)bn - 1024 + wn * 64 + n * 16 + (lane & 15);
          int h = cloc >> 6, hd = cloc & 63;
          vT[((size_t)(b * 8 + h) * 64 + hd) * T_ + t] = f2b(acc[i][n][jj]);
        }
      }
    }
  }
}

// ---------------- FF1 GEMM: 256x256 tile, 8 waves, 2-phase, in-lane SwiGLU ----------------
__global__ __launch_bounds__(512) void gemm_ff1(const u16* __restrict__ A,
    const u16* __restrict__ Bt, const float* __restrict__ b1,
    u16* __restrict__ outp) {
  __shared__ u16 lA[2][8192];
  __shared__ u16 lB[2][8192];
  const int K = 512;
  const int tid = threadIdx.x, lane = tid & 63, w = tid >> 6;   // 0..7
  const int wm = w >> 2, wn = w & 3;
  int swz = (blockIdx.x & 7) * 32 + (blockIdx.x >> 3);          // 256 blocks
  int byy = swz >> 3, bxx = swz & 7;                            // 32 x 8
  const size_t bm = (size_t)byy * 256;
  const size_t bn = (size_t)bxx * 256;

  const int r0 = tid >> 2;                                      // 0..127
  const int cs = ((tid & 3) ^ ((r0 >> 1) & 3)) * 8;
  const u16* a0 = A + (bm + r0) * K + cs;
  const u16* a1 = A + (bm + 128 + r0) * K + cs;
  const u16* b0 = Bt + (bn + r0) * K + cs;
  const u16* b1p = Bt + (bn + 128 + r0) * K + cs;

  int aoff[8], boff[4];
  #pragma unroll
  for (int i = 0; i < 8; i++) {
    int ra = wm * 128 + i * 16 + (lane & 15);
    aoff[i] = ra * 64 + (((lane >> 4) ^ ((ra >> 1) & 3)) * 16);
  }
  #pragma unroll
  for (int n = 0; n < 4; n++) {
    int rb = wn * 64 + n * 16 + (lane & 15);
    boff[n] = rb * 64 + (((lane >> 4) ^ ((rb >> 1) & 3)) * 16);
  }

  auto stage = [&](int k0, int buf) {
    char* ad = (char*)lA + buf * 16384 + w * 1024;
    char* bd = (char*)lB + buf * 16384 + w * 1024;
    gld16(a0 + k0, ad);
    gld16(a1 + k0, ad + 8192);
    gld16(b0 + k0, bd);
    gld16(b1p + k0, bd + 8192);
  };

  f32x4 acc[8][4] = {};
  stage(0, 0);
  __syncthreads();
  int cur = 0;
  for (int k0 = 0; k0 < K; k0 += 32) {
    if (k0 + 32 < K) stage(k0 + 32, cur ^ 1);
    const char* lAc = (const char*)lA + cur * 16384;
    const char* lBc = (const char*)lB + cur * 16384;
    bf16x8 bf[4];
    #pragma unroll
    for (int n = 0; n < 4; n++) bf[n] = *(const bf16x8*)(lBc + boff[n]);
    __builtin_amdgcn_s_setprio(1);
    #pragma unroll
    for (int i = 0; i < 8; i++) {
      bf16x8 af = *(const bf16x8*)(lAc + aoff[i]);
      #pragma unroll
      for (int n = 0; n < 4; n++)
        acc[i][n] = mfma16(af, bf[n], acc[i][n]);
    }
    __builtin_amdgcn_s_setprio(0);
    __syncthreads();
    cur ^= 1;
  }
  // epilogue: real col c = bn/2 + wn*32 + np*16 + q; a = acc[i][2np], g = acc[i][2np+1]
  #pragma unroll
  for (int np = 0; np < 2; np++) {
    int c = ((int)bn >> 1) + wn * 32 + np * 16 + (lane & 15);
    float bav = b1[c], bgv = b1[1024 + c];
    #pragma unroll
    for (int i = 0; i < 8; i++) {
      #pragma unroll
      for (int jj = 0; jj < 4; jj++) {
        int row = (int)bm + wm * 128 + i * 16 + (lane >> 4) * 4 + jj;
        float av = acc[i][2 * np][jj] + bav;
        float gv = acc[i][2 * np + 1][jj] + bgv;
        float sg = gv / (1.f + expf(-gv));
        outp[(size_t)row * 1024 + c] = f2b(sg * av);
      }
    }
  }
}

// ---------------- FF2 GEMM, 512 thr / 8 waves, 3-deep counted pipeline ----------------
__global__ __launch_bounds__(512) void gemm_ff2(const u16* __restrict__ A,
    const u16* __restrict__ Bt, const float* __restrict__ bias,
    float* __restrict__ C) {
  __shared__ u16 lA[3][4096];
  __shared__ u16 lB[3][4096];
  const int K = 1024, N = 512, NK = 32;
  const int tid = threadIdx.x, lane = tid & 63, w = tid >> 6;   // w 0..7
  const int wm = w >> 2, wn = w & 3;                            // 2x4 waves: 64x32 each
  int swz = (blockIdx.x & 7) * 32 + (blockIdx.x >> 3);          // 256 blocks
  int byy = swz >> 2, bxx = swz & 3;
  const size_t bm = (size_t)byy * 128;
  const size_t bn = (size_t)bxx * 128;

  const int r0 = tid >> 2;                                      // 0..127
  const int cs = ((tid & 3) ^ ((r0 >> 1) & 3)) * 8;
  const u16* a0 = A + (bm + r0) * K + cs;
  const u16* b0 = Bt + (bn + r0) * K + cs;

  int aoff[4], boff[2];
  #pragma unroll
  for (int i = 0; i < 4; i++) {
    int ra = wm * 64 + i * 16 + (lane & 15);
    aoff[i] = ra * 64 + (((lane >> 4) ^ ((ra >> 1) & 3)) * 16);
  }
  #pragma unroll
  for (int n = 0; n < 2; n++) {
    int rb = wn * 32 + n * 16 + (lane & 15);
    boff[n] = rb * 64 + (((lane >> 4) ^ ((rb >> 1) & 3)) * 16);
  }

  auto stage = [&](int j, int buf) {      // 2 loads
    gld16(a0 + j * 32, (char*)lA + buf * 8192 + w * 1024);
    gld16(b0 + j * 32, (char*)lB + buf * 8192 + w * 1024);
  };
  f32x4 acc[4][2] = {};
  auto compute = [&](int buf) {
    const char* lAc = (const char*)lA + buf * 8192;
    const char* lBc = (const char*)lB + buf * 8192;
    bf16x8 af[4], bf[2];
    #pragma unroll
    for (int i = 0; i < 4; i++) af[i] = *(const bf16x8*)(lAc + aoff[i]);
    #pragma unroll
    for (int n = 0; n < 2; n++) bf[n] = *(const bf16x8*)(lBc + boff[n]);
    __builtin_amdgcn_s_setprio(1);
    #pragma unroll
    for (int i = 0; i < 4; i++)
      #pragma unroll
      for (int n = 0; n < 2; n++)
        acc[i][n] = mfma16(af[i], bf[n], acc[i][n]);
    __builtin_amdgcn_s_setprio(0);
  };

  stage(0, 0);
  stage(1, 1);
  int cur = 0;
  for (int j = 0; j < NK - 1; j++) {
    WAITV(2);
    __builtin_amdgcn_s_barrier();
    if (j + 2 < NK) { int nb = cur + 2; if (nb >= 3) nb -= 3; stage(j + 2, nb); }
    compute(cur);
    cur = (cur + 1 == 3) ? 0 : cur + 1;
  }
  WAITV(0);
  __builtin_amdgcn_s_barrier();
  compute(cur);

  #pragma unroll
  for (int i = 0; i < 4; i++) {
    size_t mrow = bm + wm * 64 + i * 16 + (lane >> 4) * 4;
    #pragma unroll
    for (int n = 0; n < 2; n++) {
      size_t col = bn + wn * 32 + n * 16 + (lane & 15);
      float bv = bias[col];
      #pragma unroll
      for (int jj = 0; jj < 4; jj++) {
        size_t idx = (mrow + jj) * (size_t)N + col;
        C[idx] = acc[i][n][jj] + bv + C[idx];   // in-place residual
      }
    }
  }
}

// ---------------- causal flash attention + residual: out = x_value + attn ----------------
// 4 waves / 256 thr per block, 128 q-rows: each wave owns TWO 16-row strips
// (qp*128+w*16 and +64). Each staged K/V tile serves 128 rows; 4-5 independent
// blocks/CU hide each other's stage+barrier stalls (r6's 8-wave coupling split).
// Proven r5 machinery: 2-phase LDS dbuf, chunk-XOR swizzle, swapped QK^T,
// in-register softmax, cvt_pk P-pack, defer-max.
__global__ __launch_bounds__(256, 4) void attn_kernel(const u16* __restrict__ qT,
    const u16* __restrict__ kT, const u16* __restrict__ vT,
    const float* __restrict__ xv, float* __restrict__ X) {
  int s0 = (blockIdx.x & 7) * 64 + (blockIdx.x >> 3);   // 512 blocks, 8 bh per XCD
  const int bh = s0 >> 3;
  const int qp = 7 - (s0 & 7);             // LPT: longest panels first per bh
  const int b = bh >> 3, h = bh & 7;
  const int tid = threadIdx.x, lane = tid & 63, w = tid >> 6;   // 4 waves
  const int q = lane & 15, g = lane >> 4;
  __shared__ u16 lK[2][4096];
  __shared__ u16 lV[2][4096];

  const int qr0 = qp * 128 + w * 16;       // strip 0
  const int qr1 = qr0 + 64;                // strip 1
  bf16x8 qf0[2], qf1[2];
  {
    const u16* qp0 = qT + ((size_t)bh * T_ + qr0 + q) * 64 + g * 8;
    qf0[0] = *(const bf16x8*)qp0;
    qf0[1] = *(const bf16x8*)(qp0 + 32);
    const u16* qp1 = qT + ((size_t)bh * T_ + qr1 + q) * 64 + g * 8;
    qf1[0] = *(const bf16x8*)qp1;
    qf1[1] = *(const bf16x8*)(qp1 + 32);
  }
  f32x4 acc0[4] = {}, acc1[4] = {};
  float mr0 = -1e30f, lr0 = 0.f, mr1 = -1e30f, lr1 = 0.f;

  const int sr = tid >> 3;                 // 0..31
  const int scs = ((tid & 7) ^ (sr & 7)) * 8;
  const u16* kb0 = kT + ((size_t)bh * T_ + sr) * 64 + scs;
  const u16* kb1 = kT + ((size_t)bh * T_ + 32 + sr) * 64 + scs;
  const u16* vb0 = vT + ((size_t)bh * 64 + sr) * T_ + scs;
  const u16* vb1 = vT + ((size_t)bh * 64 + 32 + sr) * T_ + scs;

  auto stage = [&](int j, int buf) {
    char* kd = (char*)lK + buf * 8192 + w * 1024;
    char* vd = (char*)lV + buf * 8192 + w * 1024;
    gld16(kb0 + (size_t)j * 4096, kd);
    gld16(kb1 + (size_t)j * 4096, kd + 4096);
    gld16(vb0 + j * 64, vd);
    gld16(vb1 + j * 64, vd + 4096);
  };

  auto strip = [&](const char* lKc, const char* lVc, int j, int qrow0,
                   bf16x8 (&qf)[2], f32x4 (&acc)[4], float& mr, float& lr) {
    if (j * 64 > qrow0 + 15) return;       // strip entirely above this k-tile? no: below
    // QK^T swapped: s[n][i] = S[k = j*64 + n*16+g*4+i][qrow0+q]
    f32x4 s[4] = {};
    __builtin_amdgcn_s_setprio(1);
    #pragma unroll
    for (int ka = 0; ka < 2; ka++) {
      #pragma unroll
      for (int n = 0; n < 4; n++) {
        bf16x8 kf = *(const bf16x8*)(lKc + (n * 16 + q) * 128 +
                                     (((ka * 4 + g) ^ (q & 7)) * 16));
        s[n] = mfma16(kf, qf[ka], s[n]);
      }
    }
    __builtin_amdgcn_s_setprio(0);
    if (j * 64 + 63 > qrow0) {             // diagonal-region mask
      int qrow = qrow0 + q;
      #pragma unroll
      for (int n = 0; n < 4; n++)
        #pragma unroll
        for (int i = 0; i < 4; i++)
          if (j * 64 + n * 16 + g * 4 + i > qrow) s[n][i] = -1e30f;
    }
    // in-register softmax: one q-row per lane (+2 shfl across g-groups)
    float mt = fmaxf(fmaxf(fmaxf(s[0][0], s[0][1]), fmaxf(s[0][2], s[0][3])),
                     fmaxf(fmaxf(s[1][0], s[1][1]), fmaxf(s[1][2], s[1][3])));
    mt = fmaxf(mt, fmaxf(fmaxf(fmaxf(s[2][0], s[2][1]), fmaxf(s[2][2], s[2][3])),
                         fmaxf(fmaxf(s[3][0], s[3][1]), fmaxf(s[3][2], s[3][3]))));
    mt = fmaxf(mt, __shfl_xor(mt, 16));
    mt = fmaxf(mt, __shfl_xor(mt, 32));
    if (__any(mt > mr + 8.f)) {            // defer-max: skip rescale when growth < 2^8
      float mnew = fmaxf(mr, mt);
      float sc = exp2f(mr - mnew);
      mr = mnew;
      lr *= sc;
      #pragma unroll
      for (int t = 0; t < 4; t++) acc[t] *= sc;
    }
    float p[4][4];
    float ps = 0.f;
    #pragma unroll
    for (int n = 0; n < 4; n++)
      #pragma unroll
      for (int i = 0; i < 4; i++) { p[n][i] = exp2f(s[n][i] - mr); ps += p[n][i]; }
    ps += __shfl_xor(ps, 16);
    ps += __shfl_xor(ps, 32);
    lr += ps;
    // pack P into PV B-frags (lane-local, no shuffles)
    U8 pa[2];
    #pragma unroll
    for (int kt = 0; kt < 2; kt++) {
      pa[kt].u[0] = cvtpk(p[2 * kt][0], p[2 * kt][1]);
      pa[kt].u[1] = cvtpk(p[2 * kt][2], p[2 * kt][3]);
      pa[kt].u[2] = cvtpk(p[2 * kt + 1][0], p[2 * kt + 1][1]);
      pa[kt].u[3] = cvtpk(p[2 * kt + 1][2], p[2 * kt + 1][3]);
    }
    // PV: O^T[d][q] += V^T[d][k'] * P^T[k'][q], k'(g,e) = kt*32+(e>>2)*16+g*4+(e&3)
    __builtin_amdgcn_s_setprio(1);
    #pragma unroll
    for (int t = 0; t < 4; t++) {
      const char* vr = lVc + (t * 16 + q) * 128 + (g & 1) * 8;
      #pragma unroll
      for (int kt = 0; kt < 2; kt++) {
        u32x2 lo = *(const u32x2*)(vr + (((kt * 4 + (g >> 1)) ^ (q & 7)) * 16));
        u32x2 hi = *(const u32x2*)(vr + (((kt * 4 + 2 + (g >> 1)) ^ (q & 7)) * 16));
        U8 af;
        af.u[0] = lo[0]; af.u[1] = lo[1]; af.u[2] = hi[0]; af.u[3] = hi[1];
        acc[t] = mfma16(af.v, pa[kt].v, acc[t]);
      }
    }
    __builtin_amdgcn_s_setprio(0);
  };

  const int jmax = 2 * qp + 2;
  stage(0, 0);
  __syncthreads();
  int cur = 0;
  for (int j = 0; j < jmax; j++) {
    if (j + 1 < jmax) stage(j + 1, cur ^ 1);   // prefetch next tile under compute
    const char* lKc = (const char*)lK + cur * 8192;
    const char* lVc = (const char*)lV + cur * 8192;
    strip(lKc, lVc, j, qr0, qf0, acc0, mr0, lr0);
    strip(lKc, lVc, j, qr1, qf1, acc1, mr1, lr1);
    __syncthreads();                       // drains prefetch; publishes buf cur^1
    cur ^= 1;
  }
  // epilogue: lane owns q-rows (qr0+q, qr1+q), cols d = t*16+g*4+{0..3} -> f32x4
  {
    float inv = 1.f / lr0;
    size_t base = ((size_t)b * T_ + qr0 + q) * D_ + h * 64 + g * 4;
    #pragma unroll
    for (int t = 0; t < 4; t++) {
      f32x4 r = *(const f32x4*)(xv + base + t * 16);
      f32x4 o;
      #pragma unroll
      for (int i = 0; i < 4; i++) o[i] = r[i] + acc0[t][i] * inv;
      *(f32x4*)(X + base + t * 16) = o;
    }
  }
  {
    float inv = 1.f / lr1;
    size_t base = ((size_t)b * T_ + qr1 + q) * D_ + h * 64 + g * 4;
    #pragma unroll
    for (int t = 0; t < 4; t++) {
      f32x4 r = *(const f32x4*)(xv + base + t * 16);
      f32x4 o;
      #pragma unroll
      for (int i = 0; i < 4; i++) o[i] = r[i] + acc1[t][i] * inv;
      *(f32x4*)(X + base + t * 16) = o;
    }
  }
}

// ------------------------------- launch -------------------------------
extern "C" void kernel_launch(void* const* d_in, const int* in_sizes, int n_in,
                              void* d_out, int out_size, void* d_ws, size_t ws_size,
                              hipStream_t stream) {
  const int*   x_type   = (const int*)d_in[0];
  const float* x_value  = (const float*)d_in[1];
  const float* seq      = (const float*)d_in[2];
  const float* W_attn   = (const float*)d_in[3];
  const float* type_emb = (const float*)d_in[4];
  const float* ln1_g    = (const float*)d_in[5];
  const float* ln1_b    = (const float*)d_in[6];
  const float* ln2_g    = (const float*)d_in[7];
  const float* ln2_b    = (const float*)d_in[8];
  const float* W1       = (const float*)d_in[9];
  const float* b1       = (const float*)d_in[10];
  const float* W2       = (const float*)d_in[11];
  const float* b2       = (const float*)d_in[12];
  float* out = (float*)d_out;
  char* ws = (char*)d_ws;

  // workspace layout — total ~38.5 MiB
  u16*   WtA  = (u16*)(ws + 0);             // 1536x512 bf16  1.5 MiB
  u16*   W1i  = (u16*)(ws + 1572864);       // 2048x512 bf16 interleaved a/gate  2 MiB
  u16*   W2t  = (u16*)(ws + 3670016);       // 512x1024 bf16  1 MiB
  float* rqc  = (float*)(ws + 4718592);     // 4 rope tables, 512 KiB each
  float* rqs  = (float*)(ws + 5242880);
  float* rkc  = (float*)(ws + 5767168);
  float* rks  = (float*)(ws + 6291456);
  u16*   hbuf = (u16*)(ws + 6815744);       // 8192x512 bf16 (h, then h2)  8 MiB
  u16*   qTb  = (u16*)(ws + 15204352);      // (B,H,T,64) bf16  8 MiB
  u16*   kTb  = (u16*)(ws + 23592960);      // 8 MiB
  u16*   vTb  = (u16*)(ws + 31981568);      // (B,H,64,T) bf16  8 MiB
  u16*   ff1a = (u16*)(ws + 15204352);      // 8192x1024 bf16 16 MiB, aliases qT+kT (dead post-attn)

  prep_kernel<<<1088, 256, 0, stream>>>(W_attn, W1, W2, seq, WtA, W1i, W2t,
                                        rqc, rqs, rkc, rks);
  ln_kernel<<<B_ * T_ / 4, 256, 0, stream>>>(x_value, ln1_g, ln1_b, hbuf);
  gemm_qkv<<<768, 256, 0, stream>>>(hbuf, WtA, x_type, type_emb,
                                    rqc, rqs, rkc, rks, qTb, kTb, vTb);
  attn_kernel<<<512, 256, 0, stream>>>(qTb, kTb, vTb, x_value, out);
  ln_kernel<<<B_ * T_ / 4, 256, 0, stream>>>(out, ln2_g, ln2_b, hbuf);
  gemm_ff1<<<256, 512, 0, stream>>>(hbuf, W1i, b1, ff1a);
  gemm_ff2<<<256, 512, 0, stream>>>(ff1a, W2t, b2, out);
}

// Round 10
// 133.966 us; speedup vs baseline: 1.5062x; 1.1312x over previous
//
#include <hip/hip_runtime.h>
#include <stdint.h>
#include <math.h>

typedef unsigned short u16;
typedef unsigned int u32;
typedef __attribute__((ext_vector_type(8))) short bf16x8;   // 8 bf16 (4 VGPRs) MFMA A/B frag
typedef __attribute__((ext_vector_type(4))) float f32x4;
typedef __attribute__((ext_vector_type(2))) float f32x2;
typedef __attribute__((ext_vector_type(2))) u16 u16x2;
typedef __attribute__((ext_vector_type(8))) u16 u16x8;
typedef __attribute__((ext_vector_type(2))) u32 u32x2;

#define B_ 8
#define T_ 1024
#define D_ 512
#define H_ 8
#define TP1 1025
// q scale: 1/sqrt(64) * log2(e)  (softmax runs in exp2 domain)
#define QSCALE 0.1803368801111204f

__device__ __forceinline__ u16 f2b(float f) {           // f32 -> bf16 RNE
  union { float f; u32 u; } v; v.f = f;
  return (u16)((v.u + 0x7fffu + ((v.u >> 16) & 1u)) >> 16);
}
__device__ __forceinline__ void gld16(const void* g, void* l) {
  // async global->LDS, 16B/lane; LDS dest = wave-uniform base + lane*16
  __builtin_amdgcn_global_load_lds((const __attribute__((address_space(1))) u32*)g,
                                   (__attribute__((address_space(3))) u32*)l, 16, 0, 0);
}
__device__ __forceinline__ f32x4 mfma16(bf16x8 a, bf16x8 b, f32x4 c) {
  return __builtin_amdgcn_mfma_f32_16x16x32_bf16(a, b, c, 0, 0, 0);
}
__device__ __forceinline__ u32 cvtpk(float lo, float hi) {   // 2xf32 -> packed bf16x2 (RNE)
  u32 r;
  asm("v_cvt_pk_bf16_f32 %0, %1, %2" : "=v"(r) : "v"(lo), "v"(hi));
  return r;
}
union U8 { u32 u[4]; bf16x8 v; };

// counted-vmcnt waits: wait for the OLDEST stage only, keep the rest in flight
#define WAITV(N) asm volatile("s_waitcnt vmcnt(" #N ")" ::: "memory")

// ---------------- fused prep: tiled (coalesced) weight transposes + rope tables ----------------
__global__ __launch_bounds__(256) void prep_kernel(const float* __restrict__ W_attn,
    const float* __restrict__ W1, const float* __restrict__ W2,
    const float* __restrict__ seq,
    u16* __restrict__ WtA, u16* __restrict__ W1i, u16* __restrict__ W2t,
    float* __restrict__ cq, float* __restrict__ sq_,
    float* __restrict__ ck, float* __restrict__ sk) {
  int bid = blockIdx.x, tid = threadIdx.x;
  if (bid >= 576) {                        // rope: B*T*16 elements
    int i = (bid - 576) * 256 + tid;
    int p = i & 15, bt = i >> 4, b = bt >> 10, t = bt & 1023;
    float inv = expf(-(float)p * 0.5756462732485115f);   // 10000^(-p/16)
    float aq = seq[b * TP1 + t] * inv;
    float ak = seq[b * TP1 + t + 1] * inv;
    cq[i] = cosf(aq); sq_[i] = sinf(aq);
    ck[i] = cosf(ak); sk[i] = sinf(ak);
    return;
  }
  __shared__ u16 lt[64][65];
  const float* src; u16* dst; int ld, Kd, k0, r0; bool ilv = false;
  if (bid < 192) {            // WtA: 8 k-tiles x 24 n-tiles
    src = W_attn; dst = WtA; ld = 1536; Kd = 512;
    k0 = (bid & 7) * 64; r0 = (bid >> 3) * 64;
  } else if (bid < 448) {     // W1i: 8 k-tiles x 32 r-tiles, interleaved
    int t = bid - 192;
    src = W1; dst = W1i; ld = 2048; Kd = 512; ilv = true;
    k0 = (t & 7) * 64; r0 = (t >> 3) * 64;
  } else {                    // W2t: 16 k-tiles x 8 n-tiles
    int t = bid - 448;
    src = W2; dst = W2t; ld = 512; Kd = 1024;
    k0 = (t & 15) * 64; r0 = (t >> 4) * 64;
  }
  int nl = tid & 63;
  int scol, rloc;
  if (ilv) {
    if (nl < 32) { scol = (r0 >> 1) + nl;          rloc = ((nl >> 4) << 5) + (nl & 15); }
    else         { scol = 1024 + (r0 >> 1) + (nl - 32); rloc = (((nl - 32) >> 4) << 5) + 16 + (nl & 15); }
  } else { scol = r0 + nl; rloc = nl; }
  #pragma unroll
  for (int it = 0; it < 16; it++) {
    int kl = (tid >> 6) * 16 + it;
    lt[rloc][kl] = f2b(src[(size_t)(k0 + kl) * ld + scol]);
  }
  __syncthreads();
  #pragma unroll
  for (int it = 0; it < 16; it++) {
    int rl = (tid >> 6) * 16 + it;
    dst[(size_t)(r0 + rl) * Kd + k0 + nl] = lt[rl][nl];
  }
}

// ---------------- LayerNorm: one WAVE per row, no LDS, no barriers ----------------
__global__ __launch_bounds__(256) void ln_kernel(const float* __restrict__ x,
    const float* __restrict__ g, const float* __restrict__ bta, u16* __restrict__ out) {
  int row = blockIdx.x * 4 + (threadIdx.x >> 6);    // 8192 rows, 4 rows/block
  int lane = threadIdx.x & 63;
  const float* xr = x + (size_t)row * D_ + lane * 8;
  f32x4 v0 = *(const f32x4*)xr;
  f32x4 v1 = *(const f32x4*)(xr + 4);
  float s = 0.f, sq = 0.f;
  #pragma unroll
  for (int j = 0; j < 4; j++) { s += v0[j] + v1[j]; sq += v0[j] * v0[j] + v1[j] * v1[j]; }
  #pragma unroll
  for (int m = 1; m < 64; m <<= 1) { s += __shfl_xor(s, m); sq += __shfl_xor(sq, m); }
  float mean = s * (1.f / D_);
  float var = sq * (1.f / D_) - mean * mean;
  float rstd = rsqrtf(var + 1e-5f);
  f32x4 g0 = *(const f32x4*)(g + lane * 8);
  f32x4 g1 = *(const f32x4*)(g + lane * 8 + 4);
  f32x4 b0 = *(const f32x4*)(bta + lane * 8);
  f32x4 b1 = *(const f32x4*)(bta + lane * 8 + 4);
  u16x8 o;
  #pragma unroll
  for (int j = 0; j < 4; j++) {
    o[j]     = f2b((v0[j] - mean) * rstd * g0[j] + b0[j]);
    o[4 + j] = f2b((v1[j] - mean) * rstd * g1[j] + b1[j]);
  }
  *(u16x8*)(out + (size_t)row * D_ + lane * 8) = o;
}

// ---------------- QKV GEMM with fused type-emb + RoPE + scale + head-layout epilogue ----------------
__global__ __launch_bounds__(256) void gemm_qkv(const u16* __restrict__ A,
    const u16* __restrict__ Bt,
    const int* __restrict__ x_type, const float* __restrict__ type_emb,
    const float* __restrict__ rqc, const float* __restrict__ rqs,
    const float* __restrict__ rkc, const float* __restrict__ rks,
    u16* __restrict__ qT, u16* __restrict__ kT, u16* __restrict__ vT) {
  __shared__ u16 lA[3][4096];
  __shared__ u16 lB[3][4096];
  const int K = 512, NK = 16;
  const int tid = threadIdx.x, lane = tid & 63, w = tid >> 6;
  const int wm = w >> 1, wn = w & 1;
  int swz = (blockIdx.x & 7) * 96 + (blockIdx.x >> 3);
  int byy = swz / 12, bxx = swz - byy * 12;
  const size_t bm = (size_t)byy * 128;
  const size_t bn = (size_t)bxx * 128;

  const int r0 = tid >> 2;
  const int cs = ((tid & 3) ^ ((r0 >> 1) & 3)) * 8;
  const u16* a0 = A + (bm + r0) * K + cs;
  const u16* a1 = A + (bm + 64 + r0) * K + cs;
  const u16* b0 = Bt + (bn + r0) * K + cs;
  const u16* b1p = Bt + (bn + 64 + r0) * K + cs;

  int aoff[4], boff[4];
  #pragma unroll
  for (int i = 0; i < 4; i++) {
    int ra = wm * 64 + i * 16 + (lane & 15);
    aoff[i] = ra * 64 + (((lane >> 4) ^ ((ra >> 1) & 3)) * 16);
    int rb = wn * 64 + i * 16 + (lane & 15);
    boff[i] = rb * 64 + (((lane >> 4) ^ ((rb >> 1) & 3)) * 16);
  }

  auto stage = [&](int j, int buf) {      // 4 loads
    char* ad = (char*)lA + buf * 8192 + w * 1024;
    char* bd = (char*)lB + buf * 8192 + w * 1024;
    gld16(a0 + j * 32, ad);
    gld16(a1 + j * 32, ad + 4096);
    gld16(b0 + j * 32, bd);
    gld16(b1p + j * 32, bd + 4096);
  };
  f32x4 acc[4][4] = {};
  auto compute = [&](int buf) {
    const char* lAc = (const char*)lA + buf * 8192;
    const char* lBc = (const char*)lB + buf * 8192;
    bf16x8 af[4], bf[4];
    #pragma unroll
    for (int i = 0; i < 4; i++) af[i] = *(const bf16x8*)(lAc + aoff[i]);
    #pragma unroll
    for (int n = 0; n < 4; n++) bf[n] = *(const bf16x8*)(lBc + boff[n]);
    __builtin_amdgcn_s_setprio(1);
    #pragma unroll
    for (int i = 0; i < 4; i++)
      #pragma unroll
      for (int n = 0; n < 4; n++)
        acc[i][n] = mfma16(af[i], bf[n], acc[i][n]);
    __builtin_amdgcn_s_setprio(0);
  };

  stage(0, 0);
  stage(1, 1);
  int cur = 0;
  for (int j = 0; j < NK - 1; j++) {
    WAITV(4);
    __builtin_amdgcn_s_barrier();
    if (j + 2 < NK) { int nb = cur + 2; if (nb >= 3) nb -= 3; stage(j + 2, nb); }
    compute(cur);
    cur = (cur + 1 == 3) ? 0 : cur + 1;
  }
  WAITV(0);
  __builtin_amdgcn_s_barrier();
  compute(cur);

  // fused epilogue. block-uniform region: 0=q (cols 0..511), 1=k, 2=v
  const int region = (int)(bn >> 9);
  #pragma unroll
  for (int i = 0; i < 4; i++) {
    #pragma unroll
    for (int jj = 0; jj < 4; jj++) {
      int row = (int)bm + wm * 64 + i * 16 + (lane >> 4) * 4 + jj;   // bt index
      int b = row >> 10, t = row & 1023;
      if (region == 0) {
        int ty = x_type[b * TP1 + t];
        #pragma unroll
        for (int n = 0; n < 4; n++) {
          int cloc = (int)bn + wn * 64 + n * 16 + (lane & 15);       // 0..511
          int h = cloc >> 6, hd = cloc & 63;
          float v = acc[i][n][jj] + type_emb[(size_t)ty * 1024 + cloc];
          float vp = __shfl_xor(v, 1);
          if (hd < 32) {
            int p = hd >> 1;
            float c = rqc[row * 16 + p], s = rqs[row * 16 + p];
            v = (hd & 1) ? (v * c + vp * s) : (v * c - vp * s);
          }
          qT[((size_t)(b * 8 + h) * T_ + t) * 64 + hd] = f2b(v * QSCALE);
        }
      } else if (region == 1) {
        int ty = x_type[b * TP1 + t + 1];
        #pragma unroll
        for (int n = 0; n < 4; n++) {
          int cloc = (int)bn - 512 + wn * 64 + n * 16 + (lane & 15); // 0..511
          int h = cloc >> 6, hd = cloc & 63;
          float v = acc[i][n][jj] + type_emb[(size_t)ty * 1024 + 512 + cloc];
          float vp = __shfl_xor(v, 1);
          if (hd < 32) {
            int p = hd >> 1;
            float c = rkc[row * 16 + p], s = rks[row * 16 + p];
            v = (hd & 1) ? (v * c + vp * s) : (v * c - vp * s);
          }
          kT[((size_t)(b * 8 + h) * T_ + t) * 64 + hd] = f2b(v);
        }
      } else {
        #pragma unroll
        for (int n = 0; n < 4; n++) {
          int cloc = (int)bn - 1024 + wn * 64 + n * 16 + (lane & 15);
          int h = cloc >> 6, hd = cloc & 63;
          vT[((size_t)(b * 8 + h) * 64 + hd) * T_ + t] = f2b(acc[i][n][jj]);
        }
      }
    }
  }
}

// ---------------- FF1 GEMM on interleaved W1i: 128x128, 3-deep, in-lane SwiGLU ----------------
__global__ __launch_bounds__(256) void gemm_ff1(const u16* __restrict__ A,
    const u16* __restrict__ Bt, const float* __restrict__ b1,
    u16* __restrict__ outp) {
  __shared__ u16 lA[3][4096];
  __shared__ u16 lB[3][4096];
  const int K = 512, NK = 16;
  const int tid = threadIdx.x, lane = tid & 63, w = tid >> 6;
  const int wm = w >> 1, wn = w & 1;
  int swz = (blockIdx.x & 7) * 128 + (blockIdx.x >> 3);   // 1024 blocks
  int byy = swz >> 4, bxx = swz & 15;
  const size_t bm = (size_t)byy * 128;
  const size_t bn = (size_t)bxx * 128;

  const int r0 = tid >> 2;
  const int cs = ((tid & 3) ^ ((r0 >> 1) & 3)) * 8;
  const u16* a0 = A + (bm + r0) * K + cs;
  const u16* a1 = A + (bm + 64 + r0) * K + cs;
  const u16* b0 = Bt + (bn + r0) * K + cs;
  const u16* b1p = Bt + (bn + 64 + r0) * K + cs;

  int aoff[4], boff[4];
  #pragma unroll
  for (int i = 0; i < 4; i++) {
    int ra = wm * 64 + i * 16 + (lane & 15);
    aoff[i] = ra * 64 + (((lane >> 4) ^ ((ra >> 1) & 3)) * 16);
    int rb = wn * 64 + i * 16 + (lane & 15);
    boff[i] = rb * 64 + (((lane >> 4) ^ ((rb >> 1) & 3)) * 16);
  }

  auto stage = [&](int j, int buf) {      // 4 loads
    char* ad = (char*)lA + buf * 8192 + w * 1024;
    char* bd = (char*)lB + buf * 8192 + w * 1024;
    gld16(a0 + j * 32, ad);
    gld16(a1 + j * 32, ad + 4096);
    gld16(b0 + j * 32, bd);
    gld16(b1p + j * 32, bd + 4096);
  };
  f32x4 acc[4][4] = {};
  auto compute = [&](int buf) {
    const char* lAc = (const char*)lA + buf * 8192;
    const char* lBc = (const char*)lB + buf * 8192;
    bf16x8 af[4], bf[4];
    #pragma unroll
    for (int i = 0; i < 4; i++) af[i] = *(const bf16x8*)(lAc + aoff[i]);
    #pragma unroll
    for (int n = 0; n < 4; n++) bf[n] = *(const bf16x8*)(lBc + boff[n]);
    __builtin_amdgcn_s_setprio(1);
    #pragma unroll
    for (int i = 0; i < 4; i++)
      #pragma unroll
      for (int n = 0; n < 4; n++)
        acc[i][n] = mfma16(af[i], bf[n], acc[i][n]);
    __builtin_amdgcn_s_setprio(0);
  };

  stage(0, 0);
  stage(1, 1);
  int cur = 0;
  for (int j = 0; j < NK - 1; j++) {
    WAITV(4);
    __builtin_amdgcn_s_barrier();
    if (j + 2 < NK) { int nb = cur + 2; if (nb >= 3) nb -= 3; stage(j + 2, nb); }
    compute(cur);
    cur = (cur + 1 == 3) ? 0 : cur + 1;
  }
  WAITV(0);
  __builtin_amdgcn_s_barrier();
  compute(cur);

  // epilogue: real col c = bn/2 + wn*32 + np*16 + (lane&15); a = acc[i][2np], g = acc[i][2np+1]
  #pragma unroll
  for (int np = 0; np < 2; np++) {
    int c = ((int)bn >> 1) + wn * 32 + np * 16 + (lane & 15);
    float bav = b1[c], bgv = b1[1024 + c];
    #pragma unroll
    for (int i = 0; i < 4; i++) {
      #pragma unroll
      for (int jj = 0; jj < 4; jj++) {
        int row = (int)bm + wm * 64 + i * 16 + (lane >> 4) * 4 + jj;
        float av = acc[i][2 * np][jj] + bav;
        float gv = acc[i][2 * np + 1][jj] + bgv;
        float sg = gv / (1.f + expf(-gv));
        outp[(size_t)row * 1024 + c] = f2b(sg * av);
      }
    }
  }
}

// ---------------- FF2 GEMM, 512 thr / 8 waves, 3-deep counted pipeline ----------------
__global__ __launch_bounds__(512) void gemm_ff2(const u16* __restrict__ A,
    const u16* __restrict__ Bt, const float* __restrict__ bias,
    float* __restrict__ C) {
  __shared__ u16 lA[3][4096];
  __shared__ u16 lB[3][4096];
  const int K = 1024, N = 512, NK = 32;
  const int tid = threadIdx.x, lane = tid & 63, w = tid >> 6;   // w 0..7
  const int wm = w >> 2, wn = w & 3;                            // 2x4 waves: 64x32 each
  int swz = (blockIdx.x & 7) * 32 + (blockIdx.x >> 3);          // 256 blocks
  int byy = swz >> 2, bxx = swz & 3;
  const size_t bm = (size_t)byy * 128;
  const size_t bn = (size_t)bxx * 128;

  const int r0 = tid >> 2;                                      // 0..127
  const int cs = ((tid & 3) ^ ((r0 >> 1) & 3)) * 8;
  const u16* a0 = A + (bm + r0) * K + cs;
  const u16* b0 = Bt + (bn + r0) * K + cs;

  int aoff[4], boff[2];
  #pragma unroll
  for (int i = 0; i < 4; i++) {
    int ra = wm * 64 + i * 16 + (lane & 15);
    aoff[i] = ra * 64 + (((lane >> 4) ^ ((ra >> 1) & 3)) * 16);
  }
  #pragma unroll
  for (int n = 0; n < 2; n++) {
    int rb = wn * 32 + n * 16 + (lane & 15);
    boff[n] = rb * 64 + (((lane >> 4) ^ ((rb >> 1) & 3)) * 16);
  }

  auto stage = [&](int j, int buf) {      // 2 loads
    gld16(a0 + j * 32, (char*)lA + buf * 8192 + w * 1024);
    gld16(b0 + j * 32, (char*)lB + buf * 8192 + w * 1024);
  };
  f32x4 acc[4][2] = {};
  auto compute = [&](int buf) {
    const char* lAc = (const char*)lA + buf * 8192;
    const char* lBc = (const char*)lB + buf * 8192;
    bf16x8 af[4], bf[2];
    #pragma unroll
    for (int i = 0; i < 4; i++) af[i] = *(const bf16x8*)(lAc + aoff[i]);
    #pragma unroll
    for (int n = 0; n < 2; n++) bf[n] = *(const bf16x8*)(lBc + boff[n]);
    __builtin_amdgcn_s_setprio(1);
    #pragma unroll
    for (int i = 0; i < 4; i++)
      #pragma unroll
      for (int n = 0; n < 2; n++)
        acc[i][n] = mfma16(af[i], bf[n], acc[i][n]);
    __builtin_amdgcn_s_setprio(0);
  };

  stage(0, 0);
  stage(1, 1);
  int cur = 0;
  for (int j = 0; j < NK - 1; j++) {
    WAITV(2);
    __builtin_amdgcn_s_barrier();
    if (j + 2 < NK) { int nb = cur + 2; if (nb >= 3) nb -= 3; stage(j + 2, nb); }
    compute(cur);
    cur = (cur + 1 == 3) ? 0 : cur + 1;
  }
  WAITV(0);
  __builtin_amdgcn_s_barrier();
  compute(cur);

  #pragma unroll
  for (int i = 0; i < 4; i++) {
    size_t mrow = bm + wm * 64 + i * 16 + (lane >> 4) * 4;
    #pragma unroll
    for (int n = 0; n < 2; n++) {
      size_t col = bn + wn * 32 + n * 16 + (lane & 15);
      float bv = bias[col];
      #pragma unroll
      for (int jj = 0; jj < 4; jj++) {
        size_t idx = (mrow + jj) * (size_t)N + col;
        C[idx] = acc[i][n][jj] + bv + C[idx];   // in-place residual
      }
    }
  }
}

// ---------------- causal flash attention + residual: out = x_value + attn ----------------
// r6 structure (8 waves / 512 thr / 128 q-rows, 2-phase LDS dbuf) with KVBLK=128:
// each buffer holds TWO of the proven 8KB K sub-tiles and TWO 8KB V sub-tiles,
// halving the barrier-locked iteration count (jmax = qp+1, max 8 vs 16).
__global__ __launch_bounds__(512, 4) void attn_kernel(const u16* __restrict__ qT,
    const u16* __restrict__ kT, const u16* __restrict__ vT,
    const float* __restrict__ xv, float* __restrict__ X) {
  int s0 = (blockIdx.x & 7) * 64 + (blockIdx.x >> 3);   // 512 blocks, 8 bh per XCD
  const int xcd = blockIdx.x & 7;
  (void)xcd;
  const int bh = ((blockIdx.x & 7) << 3) + (s0 & 7);    // 8 bh per XCD
  const int qp = 7 - ((s0 >> 3) & 7);                   // true LPT: qp=7 of all bh first
  const int b = bh >> 3, h = bh & 7;
  const int tid = threadIdx.x, lane = tid & 63, w = tid >> 6;   // 8 waves
  const int q = lane & 15, g = lane >> 4;
  __shared__ u16 lK[2][8192];              // [buf][half0 8KB | half1 8KB]
  __shared__ u16 lV[2][8192];

  const int qrow0 = qp * 128 + w * 16;     // this wave's 16-row q-strip
  bf16x8 qf[2];
  {
    const u16* qp_ = qT + ((size_t)bh * T_ + qrow0 + q) * 64 + g * 8;
    qf[0] = *(const bf16x8*)qp_;
    qf[1] = *(const bf16x8*)(qp_ + 32);
  }
  f32x4 acc[4] = {};
  float mr = -1e30f, lr = 0.f;

  const int sr = tid >> 3;                 // 0..63
  const int scs = ((tid & 7) ^ (sr & 7)) * 8;
  const u16* kb = kT + ((size_t)bh * T_ + sr) * 64 + scs;
  const u16* vb = vT + ((size_t)bh * 64 + sr) * T_ + scs;

  auto stage = [&](int j, int buf) {       // K rows [j*128,+128), V cols [j*128,+128)
    char* kd = (char*)lK + buf * 16384 + w * 1024;
    char* vd = (char*)lV + buf * 16384 + w * 1024;
    gld16(kb + (size_t)j * 8192, kd);              // K half0 (rows +0..63)
    gld16(kb + (size_t)j * 8192 + 4096, kd + 8192);// K half1 (rows +64..127)
    gld16(vb + j * 128, vd);                       // V half0 (cols +0..63)
    gld16(vb + j * 128 + 64, vd + 8192);           // V half1 (cols +64..127)
  };

  const int jmax = qp + 1;
  stage(0, 0);
  __syncthreads();
  int cur = 0;
  for (int j = 0; j < jmax; j++) {
    if (j + 1 < jmax) stage(j + 1, cur ^ 1);   // prefetch next 128-tile under compute
    const char* lKc = (const char*)lK + cur * 16384;
    const char* lVc = (const char*)lV + cur * 16384;

    // QK^T swapped: s[n][i] = S[key = j*128 + n*16+g*4+i][qrow0+q]
    f32x4 s[8] = {};
    __builtin_amdgcn_s_setprio(1);
    #pragma unroll
    for (int ka = 0; ka < 2; ka++) {
      #pragma unroll
      for (int n = 0; n < 8; n++) {
        bf16x8 kf = *(const bf16x8*)(lKc + (n >> 2) * 8192 + ((n & 3) * 16 + q) * 128 +
                                     (((ka * 4 + g) ^ (q & 7)) * 16));
        s[n] = mfma16(kf, qf[ka], s[n]);
      }
    }
    __builtin_amdgcn_s_setprio(0);
    if (j == jmax - 1) {                   // diagonal-tile causal mask
      int qrow = w * 16 + q;               // key-local: n*16+g*4+i > w*16+q
      #pragma unroll
      for (int n = 0; n < 8; n++)
        #pragma unroll
        for (int i = 0; i < 4; i++)
          if (n * 16 + g * 4 + i > qrow) s[n][i] = -1e30f;
    }
    // in-register softmax: one q-row per lane (+2 shfl across g-groups)
    float mt = -1e30f;
    #pragma unroll
    for (int n = 0; n < 8; n++)
      mt = fmaxf(mt, fmaxf(fmaxf(s[n][0], s[n][1]), fmaxf(s[n][2], s[n][3])));
    mt = fmaxf(mt, __shfl_xor(mt, 16));
    mt = fmaxf(mt, __shfl_xor(mt, 32));
    if (__any(mt > mr + 8.f)) {            // defer-max: skip rescale when growth < 2^8
      float mnew = fmaxf(mr, mt);
      float sc = exp2f(mr - mnew);
      mr = mnew;
      lr *= sc;
      #pragma unroll
      for (int t = 0; t < 4; t++) acc[t] *= sc;
    }
    float ps = 0.f;
    U8 pa[4];                              // pa[kt] covers keys kt*32..kt*32+31
    #pragma unroll
    for (int kt = 0; kt < 4; kt++) {
      float p0[4], p1[4];
      #pragma unroll
      for (int i = 0; i < 4; i++) {
        p0[i] = exp2f(s[2 * kt][i] - mr);
        p1[i] = exp2f(s[2 * kt + 1][i] - mr);
        ps += p0[i] + p1[i];
      }
      pa[kt].u[0] = cvtpk(p0[0], p0[1]);
      pa[kt].u[1] = cvtpk(p0[2], p0[3]);
      pa[kt].u[2] = cvtpk(p1[0], p1[1]);
      pa[kt].u[3] = cvtpk(p1[2], p1[3]);
    }
    ps += __shfl_xor(ps, 16);
    ps += __shfl_xor(ps, 32);
    lr += ps;
    // PV: O^T[d][q] += V^T[d][k'] P^T[k'][q]; kt half = kt>>1, sub-chunk = kt&1
    __builtin_amdgcn_s_setprio(1);
    #pragma unroll
    for (int t = 0; t < 4; t++) {
      #pragma unroll
      for (int kt = 0; kt < 4; kt++) {
        const char* vrh = lVc + (kt >> 1) * 8192 + (t * 16 + q) * 128 + (g & 1) * 8;
        int ktl = kt & 1;
        u32x2 lo = *(const u32x2*)(vrh + (((ktl * 4 + (g >> 1)) ^ (q & 7)) * 16));
        u32x2 hi = *(const u32x2*)(vrh + (((ktl * 4 + 2 + (g >> 1)) ^ (q & 7)) * 16));
        U8 af;
        af.u[0] = lo[0]; af.u[1] = lo[1]; af.u[2] = hi[0]; af.u[3] = hi[1];
        acc[t] = mfma16(af.v, pa[kt].v, acc[t]);
      }
    }
    __builtin_amdgcn_s_setprio(0);
    __syncthreads();                       // drains prefetch; publishes buf cur^1
    cur ^= 1;
  }
  // epilogue: lane owns q-row (qrow0+q), cols d = t*16+g*4+{0..3} -> f32x4
  {
    float inv = 1.f / lr;
    size_t base = ((size_t)b * T_ + qrow0 + q) * D_ + h * 64 + g * 4;
    #pragma unroll
    for (int t = 0; t < 4; t++) {
      f32x4 r = *(const f32x4*)(xv + base + t * 16);
      f32x4 o;
      #pragma unroll
      for (int i = 0; i < 4; i++) o[i] = r[i] + acc[t][i] * inv;
      *(f32x4*)(X + base + t * 16) = o;
    }
  }
}

// ------------------------------- launch -------------------------------
extern "C" void kernel_launch(void* const* d_in, const int* in_sizes, int n_in,
                              void* d_out, int out_size, void* d_ws, size_t ws_size,
                              hipStream_t stream) {
  const int*   x_type   = (const int*)d_in[0];
  const float* x_value  = (const float*)d_in[1];
  const float* seq      = (const float*)d_in[2];
  const float* W_attn   = (const float*)d_in[3];
  const float* type_emb = (const float*)d_in[4];
  const float* ln1_g    = (const float*)d_in[5];
  const float* ln1_b    = (const float*)d_in[6];
  const float* ln2_g    = (const float*)d_in[7];
  const float* ln2_b    = (const float*)d_in[8];
  const float* W1       = (const float*)d_in[9];
  const float* b1       = (const float*)d_in[10];
  const float* W2       = (const float*)d_in[11];
  const float* b2       = (const float*)d_in[12];
  float* out = (float*)d_out;
  char* ws = (char*)d_ws;

  // workspace layout — total ~38.5 MiB
  u16*   WtA  = (u16*)(ws + 0);             // 1536x512 bf16  1.5 MiB
  u16*   W1i  = (u16*)(ws + 1572864);       // 2048x512 bf16 interleaved a/gate  2 MiB
  u16*   W2t  = (u16*)(ws + 3670016);       // 512x1024 bf16  1 MiB
  float* rqc  = (float*)(ws + 4718592);     // 4 rope tables, 512 KiB each
  float* rqs  = (float*)(ws + 5242880);
  float* rkc  = (float*)(ws + 5767168);
  float* rks  = (float*)(ws + 6291456);
  u16*   hbuf = (u16*)(ws + 6815744);       // 8192x512 bf16 (h, then h2)  8 MiB
  u16*   qTb  = (u16*)(ws + 15204352);      // (B,H,T,64) bf16  8 MiB
  u16*   kTb  = (u16*)(ws + 23592960);      // 8 MiB
  u16*   vTb  = (u16*)(ws + 31981568);      // (B,H,64,T) bf16  8 MiB
  u16*   ff1a = (u16*)(ws + 15204352);      // 8192x1024 bf16 16 MiB, aliases qT+kT (dead post-attn)

  prep_kernel<<<1088, 256, 0, stream>>>(W_attn, W1, W2, seq, WtA, W1i, W2t,
                                        rqc, rqs, rkc, rks);
  ln_kernel<<<B_ * T_ / 4, 256, 0, stream>>>(x_value, ln1_g, ln1_b, hbuf);
  gemm_qkv<<<768, 256, 0, stream>>>(hbuf, WtA, x_type, type_emb,
                                    rqc, rqs, rkc, rks, qTb, kTb, vTb);
  attn_kernel<<<512, 512, 0, stream>>>(qTb, kTb, vTb, x_value, out);
  ln_kernel<<<B_ * T_ / 4, 256, 0, stream>>>(out, ln2_g, ln2_b, hbuf);
  gemm_ff1<<<1024, 256, 0, stream>>>(hbuf, W1i, b1, ff1a);
  gemm_ff2<<<256, 512, 0, stream>>>(ff1a, W2t, b2, out);
}

// Round 11
// 131.658 us; speedup vs baseline: 1.5326x; 1.0175x over previous
//
#include <hip/hip_runtime.h>
#include <stdint.h>
#include <math.h>

typedef unsigned short u16;
typedef unsigned int u32;
typedef __attribute__((ext_vector_type(8))) short bf16x8;   // 8 bf16 (4 VGPRs) MFMA A/B frag
typedef __attribute__((ext_vector_type(4))) float f32x4;
typedef __attribute__((ext_vector_type(2))) float f32x2;
typedef __attribute__((ext_vector_type(2))) u16 u16x2;
typedef __attribute__((ext_vector_type(8))) u16 u16x8;
typedef __attribute__((ext_vector_type(2))) u32 u32x2;

#define B_ 8
#define T_ 1024
#define D_ 512
#define H_ 8
#define TP1 1025
// q scale: 1/sqrt(64) * log2(e)  (softmax runs in exp2 domain)
#define QSCALE 0.1803368801111204f

__device__ __forceinline__ u16 f2b(float f) {           // f32 -> bf16 RNE
  union { float f; u32 u; } v; v.f = f;
  return (u16)((v.u + 0x7fffu + ((v.u >> 16) & 1u)) >> 16);
}
__device__ __forceinline__ void gld16(const void* g, void* l) {
  // async global->LDS, 16B/lane; LDS dest = wave-uniform base + lane*16
  __builtin_amdgcn_global_load_lds((const __attribute__((address_space(1))) u32*)g,
                                   (__attribute__((address_space(3))) u32*)l, 16, 0, 0);
}
__device__ __forceinline__ f32x4 mfma16(bf16x8 a, bf16x8 b, f32x4 c) {
  return __builtin_amdgcn_mfma_f32_16x16x32_bf16(a, b, c, 0, 0, 0);
}
__device__ __forceinline__ u32 cvtpk(float lo, float hi) {   // 2xf32 -> packed bf16x2 (RNE)
  u32 r;
  asm("v_cvt_pk_bf16_f32 %0, %1, %2" : "=v"(r) : "v"(lo), "v"(hi));
  return r;
}
union U8 { u32 u[4]; bf16x8 v; };

// counted-vmcnt waits: wait for the OLDEST stage only, keep the rest in flight
#define WAITV(N) asm volatile("s_waitcnt vmcnt(" #N ")" ::: "memory")

// ---------------- fused prep: tiled (coalesced) weight transposes + rope tables ----------------
__global__ __launch_bounds__(256) void prep_kernel(const float* __restrict__ W_attn,
    const float* __restrict__ W1, const float* __restrict__ W2,
    const float* __restrict__ seq,
    u16* __restrict__ WtA, u16* __restrict__ W1i, u16* __restrict__ W2t,
    float* __restrict__ cq, float* __restrict__ sq_,
    float* __restrict__ ck, float* __restrict__ sk) {
  int bid = blockIdx.x, tid = threadIdx.x;
  if (bid >= 576) {                        // rope: B*T*16 elements
    int i = (bid - 576) * 256 + tid;
    int p = i & 15, bt = i >> 4, b = bt >> 10, t = bt & 1023;
    float inv = expf(-(float)p * 0.5756462732485115f);   // 10000^(-p/16)
    float aq = seq[b * TP1 + t] * inv;
    float ak = seq[b * TP1 + t + 1] * inv;
    cq[i] = cosf(aq); sq_[i] = sinf(aq);
    ck[i] = cosf(ak); sk[i] = sinf(ak);
    return;
  }
  __shared__ u16 lt[64][65];
  const float* src; u16* dst; int ld, Kd, k0, r0; bool ilv = false;
  if (bid < 192) {            // WtA: 8 k-tiles x 24 n-tiles
    src = W_attn; dst = WtA; ld = 1536; Kd = 512;
    k0 = (bid & 7) * 64; r0 = (bid >> 3) * 64;
  } else if (bid < 448) {     // W1i: 8 k-tiles x 32 r-tiles, interleaved
    int t = bid - 192;
    src = W1; dst = W1i; ld = 2048; Kd = 512; ilv = true;
    k0 = (t & 7) * 64; r0 = (t >> 3) * 64;
  } else {                    // W2t: 16 k-tiles x 8 n-tiles
    int t = bid - 448;
    src = W2; dst = W2t; ld = 512; Kd = 1024;
    k0 = (t & 15) * 64; r0 = (t >> 4) * 64;
  }
  int nl = tid & 63;
  int scol, rloc;
  if (ilv) {
    if (nl < 32) { scol = (r0 >> 1) + nl;          rloc = ((nl >> 4) << 5) + (nl & 15); }
    else         { scol = 1024 + (r0 >> 1) + (nl - 32); rloc = (((nl - 32) >> 4) << 5) + 16 + (nl & 15); }
  } else { scol = r0 + nl; rloc = nl; }
  #pragma unroll
  for (int it = 0; it < 16; it++) {
    int kl = (tid >> 6) * 16 + it;
    lt[rloc][kl] = f2b(src[(size_t)(k0 + kl) * ld + scol]);
  }
  __syncthreads();
  #pragma unroll
  for (int it = 0; it < 16; it++) {
    int rl = (tid >> 6) * 16 + it;
    dst[(size_t)(r0 + rl) * Kd + k0 + nl] = lt[rl][nl];
  }
}

// ---------------- LayerNorm: one WAVE per row, no LDS, no barriers ----------------
__global__ __launch_bounds__(256) void ln_kernel(const float* __restrict__ x,
    const float* __restrict__ g, const float* __restrict__ bta, u16* __restrict__ out) {
  int row = blockIdx.x * 4 + (threadIdx.x >> 6);    // 8192 rows, 4 rows/block
  int lane = threadIdx.x & 63;
  const float* xr = x + (size_t)row * D_ + lane * 8;
  f32x4 v0 = *(const f32x4*)xr;
  f32x4 v1 = *(const f32x4*)(xr + 4);
  float s = 0.f, sq = 0.f;
  #pragma unroll
  for (int j = 0; j < 4; j++) { s += v0[j] + v1[j]; sq += v0[j] * v0[j] + v1[j] * v1[j]; }
  #pragma unroll
  for (int m = 1; m < 64; m <<= 1) { s += __shfl_xor(s, m); sq += __shfl_xor(sq, m); }
  float mean = s * (1.f / D_);
  float var = sq * (1.f / D_) - mean * mean;
  float rstd = rsqrtf(var + 1e-5f);
  f32x4 g0 = *(const f32x4*)(g + lane * 8);
  f32x4 g1 = *(const f32x4*)(g + lane * 8 + 4);
  f32x4 b0 = *(const f32x4*)(bta + lane * 8);
  f32x4 b1 = *(const f32x4*)(bta + lane * 8 + 4);
  u16x8 o;
  #pragma unroll
  for (int j = 0; j < 4; j++) {
    o[j]     = f2b((v0[j] - mean) * rstd * g0[j] + b0[j]);
    o[4 + j] = f2b((v1[j] - mean) * rstd * g1[j] + b1[j]);
  }
  *(u16x8*)(out + (size_t)row * D_ + lane * 8) = o;
}

// ---------------- QKV GEMM with fused type-emb + RoPE + scale + head-layout epilogue ----------------
__global__ __launch_bounds__(256) void gemm_qkv(const u16* __restrict__ A,
    const u16* __restrict__ Bt,
    const int* __restrict__ x_type, const float* __restrict__ type_emb,
    const float* __restrict__ rqc, const float* __restrict__ rqs,
    const float* __restrict__ rkc, const float* __restrict__ rks,
    u16* __restrict__ qT, u16* __restrict__ kT, u16* __restrict__ vT) {
  __shared__ u16 lA[3][4096];
  __shared__ u16 lB[3][4096];
  const int K = 512, NK = 16;
  const int tid = threadIdx.x, lane = tid & 63, w = tid >> 6;
  const int wm = w >> 1, wn = w & 1;
  int swz = (blockIdx.x & 7) * 96 + (blockIdx.x >> 3);
  int byy = swz / 12, bxx = swz - byy * 12;
  const size_t bm = (size_t)byy * 128;
  const size_t bn = (size_t)bxx * 128;

  const int r0 = tid >> 2;
  const int cs = ((tid & 3) ^ ((r0 >> 1) & 3)) * 8;
  const u16* a0 = A + (bm + r0) * K + cs;
  const u16* a1 = A + (bm + 64 + r0) * K + cs;
  const u16* b0 = Bt + (bn + r0) * K + cs;
  const u16* b1p = Bt + (bn + 64 + r0) * K + cs;

  int aoff[4], boff[4];
  #pragma unroll
  for (int i = 0; i < 4; i++) {
    int ra = wm * 64 + i * 16 + (lane & 15);
    aoff[i] = ra * 64 + (((lane >> 4) ^ ((ra >> 1) & 3)) * 16);
    int rb = wn * 64 + i * 16 + (lane & 15);
    boff[i] = rb * 64 + (((lane >> 4) ^ ((rb >> 1) & 3)) * 16);
  }

  auto stage = [&](int j, int buf) {      // 4 loads
    char* ad = (char*)lA + buf * 8192 + w * 1024;
    char* bd = (char*)lB + buf * 8192 + w * 1024;
    gld16(a0 + j * 32, ad);
    gld16(a1 + j * 32, ad + 4096);
    gld16(b0 + j * 32, bd);
    gld16(b1p + j * 32, bd + 4096);
  };
  f32x4 acc[4][4] = {};
  auto compute = [&](int buf) {
    const char* lAc = (const char*)lA + buf * 8192;
    const char* lBc = (const char*)lB + buf * 8192;
    bf16x8 af[4], bf[4];
    #pragma unroll
    for (int i = 0; i < 4; i++) af[i] = *(const bf16x8*)(lAc + aoff[i]);
    #pragma unroll
    for (int n = 0; n < 4; n++) bf[n] = *(const bf16x8*)(lBc + boff[n]);
    __builtin_amdgcn_s_setprio(1);
    #pragma unroll
    for (int i = 0; i < 4; i++)
      #pragma unroll
      for (int n = 0; n < 4; n++)
        acc[i][n] = mfma16(af[i], bf[n], acc[i][n]);
    __builtin_amdgcn_s_setprio(0);
  };

  stage(0, 0);
  stage(1, 1);
  int cur = 0;
  for (int j = 0; j < NK - 1; j++) {
    WAITV(4);
    __builtin_amdgcn_s_barrier();
    if (j + 2 < NK) { int nb = cur + 2; if (nb >= 3) nb -= 3; stage(j + 2, nb); }
    compute(cur);
    cur = (cur + 1 == 3) ? 0 : cur + 1;
  }
  WAITV(0);
  __builtin_amdgcn_s_barrier();
  compute(cur);

  // fused epilogue. block-uniform region: 0=q (cols 0..511), 1=k, 2=v
  const int region = (int)(bn >> 9);
  #pragma unroll
  for (int i = 0; i < 4; i++) {
    #pragma unroll
    for (int jj = 0; jj < 4; jj++) {
      int row = (int)bm + wm * 64 + i * 16 + (lane >> 4) * 4 + jj;   // bt index
      int b = row >> 10, t = row & 1023;
      if (region == 0) {
        int ty = x_type[b * TP1 + t];
        #pragma unroll
        for (int n = 0; n < 4; n++) {
          int cloc = (int)bn + wn * 64 + n * 16 + (lane & 15);       // 0..511
          int h = cloc >> 6, hd = cloc & 63;
          float v = acc[i][n][jj] + type_emb[(size_t)ty * 1024 + cloc];
          float vp = __shfl_xor(v, 1);
          if (hd < 32) {
            int p = hd >> 1;
            float c = rqc[row * 16 + p], s = rqs[row * 16 + p];
            v = (hd & 1) ? (v * c + vp * s) : (v * c - vp * s);
          }
          qT[((size_t)(b * 8 + h) * T_ + t) * 64 + hd] = f2b(v * QSCALE);
        }
      } else if (region == 1) {
        int ty = x_type[b * TP1 + t + 1];
        #pragma unroll
        for (int n = 0; n < 4; n++) {
          int cloc = (int)bn - 512 + wn * 64 + n * 16 + (lane & 15); // 0..511
          int h = cloc >> 6, hd = cloc & 63;
          float v = acc[i][n][jj] + type_emb[(size_t)ty * 1024 + 512 + cloc];
          float vp = __shfl_xor(v, 1);
          if (hd < 32) {
            int p = hd >> 1;
            float c = rkc[row * 16 + p], s = rks[row * 16 + p];
            v = (hd & 1) ? (v * c + vp * s) : (v * c - vp * s);
          }
          kT[((size_t)(b * 8 + h) * T_ + t) * 64 + hd] = f2b(v);
        }
      } else {
        #pragma unroll
        for (int n = 0; n < 4; n++) {
          int cloc = (int)bn - 1024 + wn * 64 + n * 16 + (lane & 15);
          int h = cloc >> 6, hd = cloc & 63;
          vT[((size_t)(b * 8 + h) * 64 + hd) * T_ + t] = f2b(acc[i][n][jj]);
        }
      }
    }
  }
}

// ---------------- FF1 GEMM: BM=256 x BN=128, BK=32, 512 thr / 8 waves, 2-phase ----------------
// Wave (wm,wn) of 2x4 owns 128 rows x 32 interleaved cols (16 real cols a+gate).
// Grid 512 blocks = 2/CU resident (16 waves/CU) vs previous 3x256-thr (12 waves).
__global__ __launch_bounds__(512) void gemm_ff1(const u16* __restrict__ A,
    const u16* __restrict__ Bt, const float* __restrict__ b1,
    u16* __restrict__ outp) {
  __shared__ u16 lA[2][8192];              // 256 rows x 32 cols per buf (16KB)
  __shared__ u16 lB[2][4096];              // 128 rows x 32 cols per buf (8KB)
  const int K = 512;
  const int tid = threadIdx.x, lane = tid & 63, w = tid >> 6;   // 8 waves
  const int wm = w >> 2, wn = w & 3;
  int swz = (blockIdx.x & 7) * 64 + (blockIdx.x >> 3);          // 512 blocks
  int byy = swz >> 4, bxx = swz & 15;                           // 32 x 16
  const size_t bm = (size_t)byy * 256;
  const size_t bn = (size_t)bxx * 128;

  const int r0 = tid >> 2;                                      // 0..127
  const int cs = ((tid & 3) ^ ((r0 >> 1) & 3)) * 8;
  const u16* a0 = A + (bm + r0) * K + cs;
  const u16* a1 = A + (bm + 128 + r0) * K + cs;
  const u16* b0 = Bt + (bn + r0) * K + cs;

  int aoff[8], boff[2];
  #pragma unroll
  for (int i = 0; i < 8; i++) {
    int ra = wm * 128 + i * 16 + (lane & 15);
    aoff[i] = ra * 64 + (((lane >> 4) ^ ((ra >> 1) & 3)) * 16);
  }
  #pragma unroll
  for (int n = 0; n < 2; n++) {
    int rb = wn * 32 + n * 16 + (lane & 15);
    boff[n] = rb * 64 + (((lane >> 4) ^ ((rb >> 1) & 3)) * 16);
  }

  auto stage = [&](int k0, int buf) {      // 3 gld16 calls (8KB each)
    char* ad = (char*)lA + buf * 16384 + w * 1024;
    char* bd = (char*)lB + buf * 8192 + w * 1024;
    gld16(a0 + k0, ad);                    // A rows 0..127
    gld16(a1 + k0, ad + 8192);             // A rows 128..255
    gld16(b0 + k0, bd);                    // B rows 0..127
  };

  f32x4 acc[8][2] = {};
  stage(0, 0);
  __syncthreads();
  int cur = 0;
  for (int k0 = 0; k0 < K; k0 += 32) {
    if (k0 + 32 < K) stage(k0 + 32, cur ^ 1);
    const char* lAc = (const char*)lA + cur * 16384;
    const char* lBc = (const char*)lB + cur * 8192;
    bf16x8 bf[2];
    #pragma unroll
    for (int n = 0; n < 2; n++) bf[n] = *(const bf16x8*)(lBc + boff[n]);
    __builtin_amdgcn_s_setprio(1);
    #pragma unroll
    for (int i = 0; i < 8; i++) {
      bf16x8 af = *(const bf16x8*)(lAc + aoff[i]);
      acc[i][0] = mfma16(af, bf[0], acc[i][0]);
      acc[i][1] = mfma16(af, bf[1], acc[i][1]);
    }
    __builtin_amdgcn_s_setprio(0);
    __syncthreads();
    cur ^= 1;
  }
  // epilogue: real col c = bn/2 + wn*16 + (lane&15); a = acc[i][0], g = acc[i][1]
  {
    int c = ((int)bn >> 1) + wn * 16 + (lane & 15);
    float bav = b1[c], bgv = b1[1024 + c];
    #pragma unroll
    for (int i = 0; i < 8; i++) {
      #pragma unroll
      for (int jj = 0; jj < 4; jj++) {
        int row = (int)bm + wm * 128 + i * 16 + (lane >> 4) * 4 + jj;
        float av = acc[i][0][jj] + bav;
        float gv = acc[i][1][jj] + bgv;
        float sg = gv / (1.f + expf(-gv));
        outp[(size_t)row * 1024 + c] = f2b(sg * av);
      }
    }
  }
}

// ---------------- FF2 GEMM, 512 thr / 8 waves, 3-deep counted pipeline ----------------
__global__ __launch_bounds__(512) void gemm_ff2(const u16* __restrict__ A,
    const u16* __restrict__ Bt, const float* __restrict__ bias,
    float* __restrict__ C) {
  __shared__ u16 lA[3][4096];
  __shared__ u16 lB[3][4096];
  const int K = 1024, N = 512, NK = 32;
  const int tid = threadIdx.x, lane = tid & 63, w = tid >> 6;   // w 0..7
  const int wm = w >> 2, wn = w & 3;                            // 2x4 waves: 64x32 each
  int swz = (blockIdx.x & 7) * 32 + (blockIdx.x >> 3);          // 256 blocks
  int byy = swz >> 2, bxx = swz & 3;
  const size_t bm = (size_t)byy * 128;
  const size_t bn = (size_t)bxx * 128;

  const int r0 = tid >> 2;                                      // 0..127
  const int cs = ((tid & 3) ^ ((r0 >> 1) & 3)) * 8;
  const u16* a0 = A + (bm + r0) * K + cs;
  const u16* b0 = Bt + (bn + r0) * K + cs;

  int aoff[4], boff[2];
  #pragma unroll
  for (int i = 0; i < 4; i++) {
    int ra = wm * 64 + i * 16 + (lane & 15);
    aoff[i] = ra * 64 + (((lane >> 4) ^ ((ra >> 1) & 3)) * 16);
  }
  #pragma unroll
  for (int n = 0; n < 2; n++) {
    int rb = wn * 32 + n * 16 + (lane & 15);
    boff[n] = rb * 64 + (((lane >> 4) ^ ((rb >> 1) & 3)) * 16);
  }

  auto stage = [&](int j, int buf) {      // 2 loads
    gld16(a0 + j * 32, (char*)lA + buf * 8192 + w * 1024);
    gld16(b0 + j * 32, (char*)lB + buf * 8192 + w * 1024);
  };
  f32x4 acc[4][2] = {};
  auto compute = [&](int buf) {
    const char* lAc = (const char*)lA + buf * 8192;
    const char* lBc = (const char*)lB + buf * 8192;
    bf16x8 af[4], bf[2];
    #pragma unroll
    for (int i = 0; i < 4; i++) af[i] = *(const bf16x8*)(lAc + aoff[i]);
    #pragma unroll
    for (int n = 0; n < 2; n++) bf[n] = *(const bf16x8*)(lBc + boff[n]);
    __builtin_amdgcn_s_setprio(1);
    #pragma unroll
    for (int i = 0; i < 4; i++)
      #pragma unroll
      for (int n = 0; n < 2; n++)
        acc[i][n] = mfma16(af[i], bf[n], acc[i][n]);
    __builtin_amdgcn_s_setprio(0);
  };

  stage(0, 0);
  stage(1, 1);
  int cur = 0;
  for (int j = 0; j < NK - 1; j++) {
    WAITV(2);
    __builtin_amdgcn_s_barrier();
    if (j + 2 < NK) { int nb = cur + 2; if (nb >= 3) nb -= 3; stage(j + 2, nb); }
    compute(cur);
    cur = (cur + 1 == 3) ? 0 : cur + 1;
  }
  WAITV(0);
  __builtin_amdgcn_s_barrier();
  compute(cur);

  #pragma unroll
  for (int i = 0; i < 4; i++) {
    size_t mrow = bm + wm * 64 + i * 16 + (lane >> 4) * 4;
    #pragma unroll
    for (int n = 0; n < 2; n++) {
      size_t col = bn + wn * 32 + n * 16 + (lane & 15);
      float bv = bias[col];
      #pragma unroll
      for (int jj = 0; jj < 4; jj++) {
        size_t idx = (mrow + jj) * (size_t)N + col;
        C[idx] = acc[i][n][jj] + bv + C[idx];   // in-place residual
      }
    }
  }
}

// ---------------- causal flash attention + residual: out = x_value + attn ----------------
// 8 waves / 512 thr / 128 q-rows, 2-phase LDS dbuf with KVBLK=128 (two proven 8KB
// sub-tiles per buffer): jmax = qp+1 barrier-locked iterations (max 8).
__global__ __launch_bounds__(512, 4) void attn_kernel(const u16* __restrict__ qT,
    const u16* __restrict__ kT, const u16* __restrict__ vT,
    const float* __restrict__ xv, float* __restrict__ X) {
  int s0 = (blockIdx.x & 7) * 64 + (blockIdx.x >> 3);   // 512 blocks, 8 bh per XCD
  const int bh = ((blockIdx.x & 7) << 3) + (s0 & 7);    // 8 bh per XCD
  const int qp = 7 - ((s0 >> 3) & 7);                   // true LPT: qp=7 of all bh first
  const int b = bh >> 3, h = bh & 7;
  const int tid = threadIdx.x, lane = tid & 63, w = tid >> 6;   // 8 waves
  const int q = lane & 15, g = lane >> 4;
  __shared__ u16 lK[2][8192];              // [buf][half0 8KB | half1 8KB]
  __shared__ u16 lV[2][8192];

  const int qrow0 = qp * 128 + w * 16;     // this wave's 16-row q-strip
  bf16x8 qf[2];
  {
    const u16* qp_ = qT + ((size_t)bh * T_ + qrow0 + q) * 64 + g * 8;
    qf[0] = *(const bf16x8*)qp_;
    qf[1] = *(const bf16x8*)(qp_ + 32);
  }
  f32x4 acc[4] = {};
  float mr = -1e30f, lr = 0.f;

  const int sr = tid >> 3;                 // 0..63
  const int scs = ((tid & 7) ^ (sr & 7)) * 8;
  const u16* kb = kT + ((size_t)bh * T_ + sr) * 64 + scs;
  const u16* vb = vT + ((size_t)bh * 64 + sr) * T_ + scs;

  auto stage = [&](int j, int buf) {       // K rows [j*128,+128), V cols [j*128,+128)
    char* kd = (char*)lK + buf * 16384 + w * 1024;
    char* vd = (char*)lV + buf * 16384 + w * 1024;
    gld16(kb + (size_t)j * 8192, kd);              // K half0 (rows +0..63)
    gld16(kb + (size_t)j * 8192 + 4096, kd + 8192);// K half1 (rows +64..127)
    gld16(vb + j * 128, vd);                       // V half0 (cols +0..63)
    gld16(vb + j * 128 + 64, vd + 8192);           // V half1 (cols +64..127)
  };

  const int jmax = qp + 1;
  stage(0, 0);
  __syncthreads();
  int cur = 0;
  for (int j = 0; j < jmax; j++) {
    if (j + 1 < jmax) stage(j + 1, cur ^ 1);   // prefetch next 128-tile under compute
    const char* lKc = (const char*)lK + cur * 16384;
    const char* lVc = (const char*)lV + cur * 16384;

    // QK^T swapped: s[n][i] = S[key = j*128 + n*16+g*4+i][qrow0+q]
    f32x4 s[8] = {};
    __builtin_amdgcn_s_setprio(1);
    #pragma unroll
    for (int ka = 0; ka < 2; ka++) {
      #pragma unroll
      for (int n = 0; n < 8; n++) {
        bf16x8 kf = *(const bf16x8*)(lKc + (n >> 2) * 8192 + ((n & 3) * 16 + q) * 128 +
                                     (((ka * 4 + g) ^ (q & 7)) * 16));
        s[n] = mfma16(kf, qf[ka], s[n]);
      }
    }
    __builtin_amdgcn_s_setprio(0);
    if (j == jmax - 1) {                   // diagonal-tile causal mask
      int qrow = w * 16 + q;               // key-local: n*16+g*4+i > w*16+q
      #pragma unroll
      for (int n = 0; n < 8; n++)
        #pragma unroll
        for (int i = 0; i < 4; i++)
          if (n * 16 + g * 4 + i > qrow) s[n][i] = -1e30f;
    }
    // in-register softmax: one q-row per lane (+2 shfl across g-groups)
    float mt = -1e30f;
    #pragma unroll
    for (int n = 0; n < 8; n++)
      mt = fmaxf(mt, fmaxf(fmaxf(s[n][0], s[n][1]), fmaxf(s[n][2], s[n][3])));
    mt = fmaxf(mt, __shfl_xor(mt, 16));
    mt = fmaxf(mt, __shfl_xor(mt, 32));
    if (__any(mt > mr + 8.f)) {            // defer-max: skip rescale when growth < 2^8
      float mnew = fmaxf(mr, mt);
      float sc = exp2f(mr - mnew);
      mr = mnew;
      lr *= sc;
      #pragma unroll
      for (int t = 0; t < 4; t++) acc[t] *= sc;
    }
    float ps = 0.f;
    U8 pa[4];                              // pa[kt] covers keys kt*32..kt*32+31
    #pragma unroll
    for (int kt = 0; kt < 4; kt++) {
      float p0[4], p1[4];
      #pragma unroll
      for (int i = 0; i < 4; i++) {
        p0[i] = exp2f(s[2 * kt][i] - mr);
        p1[i] = exp2f(s[2 * kt + 1][i] - mr);
        ps += p0[i] + p1[i];
      }
      pa[kt].u[0] = cvtpk(p0[0], p0[1]);
      pa[kt].u[1] = cvtpk(p0[2], p0[3]);
      pa[kt].u[2] = cvtpk(p1[0], p1[1]);
      pa[kt].u[3] = cvtpk(p1[2], p1[3]);
    }
    ps += __shfl_xor(ps, 16);
    ps += __shfl_xor(ps, 32);
    lr += ps;
    // PV: O^T[d][q] += V^T[d][k'] P^T[k'][q]; kt half = kt>>1, sub-chunk = kt&1
    __builtin_amdgcn_s_setprio(1);
    #pragma unroll
    for (int t = 0; t < 4; t++) {
      #pragma unroll
      for (int kt = 0; kt < 4; kt++) {
        const char* vrh = lVc + (kt >> 1) * 8192 + (t * 16 + q) * 128 + (g & 1) * 8;
        int ktl = kt & 1;
        u32x2 lo = *(const u32x2*)(vrh + (((ktl * 4 + (g >> 1)) ^ (q & 7)) * 16));
        u32x2 hi = *(const u32x2*)(vrh + (((ktl * 4 + 2 + (g >> 1)) ^ (q & 7)) * 16));
        U8 af;
        af.u[0] = lo[0]; af.u[1] = lo[1]; af.u[2] = hi[0]; af.u[3] = hi[1];
        acc[t] = mfma16(af.v, pa[kt].v, acc[t]);
      }
    }
    __builtin_amdgcn_s_setprio(0);
    __syncthreads();                       // drains prefetch; publishes buf cur^1
    cur ^= 1;
  }
  // epilogue: lane owns q-row (qrow0+q), cols d = t*16+g*4+{0..3} -> f32x4
  {
    float inv = 1.f / lr;
    size_t base = ((size_t)b * T_ + qrow0 + q) * D_ + h * 64 + g * 4;
    #pragma unroll
    for (int t = 0; t < 4; t++) {
      f32x4 r = *(const f32x4*)(xv + base + t * 16);
      f32x4 o;
      #pragma unroll
      for (int i = 0; i < 4; i++) o[i] = r[i] + acc[t][i] * inv;
      *(f32x4*)(X + base + t * 16) = o;
    }
  }
}

// ------------------------------- launch -------------------------------
extern "C" void kernel_launch(void* const* d_in, const int* in_sizes, int n_in,
                              void* d_out, int out_size, void* d_ws, size_t ws_size,
                              hipStream_t stream) {
  const int*   x_type   = (const int*)d_in[0];
  const float* x_value  = (const float*)d_in[1];
  const float* seq      = (const float*)d_in[2];
  const float* W_attn   = (const float*)d_in[3];
  const float* type_emb = (const float*)d_in[4];
  const float* ln1_g    = (const float*)d_in[5];
  const float* ln1_b    = (const float*)d_in[6];
  const float* ln2_g    = (const float*)d_in[7];
  const float* ln2_b    = (const float*)d_in[8];
  const float* W1       = (const float*)d_in[9];
  const float* b1       = (const float*)d_in[10];
  const float* W2       = (const float*)d_in[11];
  const float* b2       = (const float*)d_in[12];
  float* out = (float*)d_out;
  char* ws = (char*)d_ws;

  // workspace layout — total ~38.5 MiB
  u16*   WtA  = (u16*)(ws + 0);             // 1536x512 bf16  1.5 MiB
  u16*   W1i  = (u16*)(ws + 1572864);       // 2048x512 bf16 interleaved a/gate  2 MiB
  u16*   W2t  = (u16*)(ws + 3670016);       // 512x1024 bf16  1 MiB
  float* rqc  = (float*)(ws + 4718592);     // 4 rope tables, 512 KiB each
  float* rqs  = (float*)(ws + 5242880);
  float* rkc  = (float*)(ws + 5767168);
  float* rks  = (float*)(ws + 6291456);
  u16*   hbuf = (u16*)(ws + 6815744);       // 8192x512 bf16 (h, then h2)  8 MiB
  u16*   qTb  = (u16*)(ws + 15204352);      // (B,H,T,64) bf16  8 MiB
  u16*   kTb  = (u16*)(ws + 23592960);      // 8 MiB
  u16*   vTb  = (u16*)(ws + 31981568);      // (B,H,64,T) bf16  8 MiB
  u16*   ff1a = (u16*)(ws + 15204352);      // 8192x1024 bf16 16 MiB, aliases qT+kT (dead post-attn)

  prep_kernel<<<1088, 256, 0, stream>>>(W_attn, W1, W2, seq, WtA, W1i, W2t,
                                        rqc, rqs, rkc, rks);
  ln_kernel<<<B_ * T_ / 4, 256, 0, stream>>>(x_value, ln1_g, ln1_b, hbuf);
  gemm_qkv<<<768, 256, 0, stream>>>(hbuf, WtA, x_type, type_emb,
                                    rqc, rqs, rkc, rks, qTb, kTb, vTb);
  attn_kernel<<<512, 512, 0, stream>>>(qTb, kTb, vTb, x_value, out);
  ln_kernel<<<B_ * T_ / 4, 256, 0, stream>>>(out, ln2_g, ln2_b, hbuf);
  gemm_ff1<<<512, 512, 0, stream>>>(hbuf, W1i, b1, ff1a);
  gemm_ff2<<<256, 512, 0, stream>>>(ff1a, W2t, b2, out);
}